// Round 1
// baseline (1383.060 us; speedup 1.0000x reference)
//
#include <hip/hip_runtime.h>

typedef unsigned short u16;
typedef unsigned int u32;
typedef __attribute__((ext_vector_type(4))) float f32x4;
typedef __attribute__((ext_vector_type(8))) short short8;
typedef __attribute__((ext_vector_type(4))) unsigned short u16x4;

// ---------- helpers ----------
__device__ __forceinline__ u16 f2b(float f){
  u32 u = __float_as_uint(f);
  u = (u + 0x7FFFu + ((u >> 16) & 1u)) >> 16;   // RNE
  return (u16)u;
}
__device__ __forceinline__ float b2f(u16 h){ return __uint_as_float(((u32)h) << 16); }

__device__ __forceinline__ void gload16(const void* g, void* l){
  __builtin_amdgcn_global_load_lds((__attribute__((address_space(1))) void*)(g),
                                   (__attribute__((address_space(3))) void*)(l), 16, 0, 0);
}

// ---------- x f32 -> bf16 ----------
__global__ __launch_bounds__(256) void convert_x_kernel(const float* __restrict__ x,
                                                        u16* __restrict__ xb){
  int g = blockIdx.x * 256 + threadIdx.x;           // 1,048,576 threads, 8 elems each
  const float4* p = (const float4*)x + (size_t)g * 2;
  float4 a = p[0], b = p[1];
  u16x4 o0 = { f2b(a.x), f2b(a.y), f2b(a.z), f2b(a.w) };
  u16x4 o1 = { f2b(b.x), f2b(b.y), f2b(b.z), f2b(b.w) };
  ((u16x4*)xb)[(size_t)g * 2]     = o0;
  ((u16x4*)xb)[(size_t)g * 2 + 1] = o1;
}

// ---------- W f32 [R][C] -> bf16 transposed [C][R], per expert ----------
__global__ __launch_bounds__(256) void transpose_cvt_kernel(const float* __restrict__ src,
                                                            u16* __restrict__ dst,
                                                            int R, int C){
  __shared__ float t[32][33];
  int e = blockIdx.z;
  size_t eo = (size_t)R * C * e;
  int c0 = blockIdx.x * 32, r0 = blockIdx.y * 32;
  int tx = threadIdx.x, ty = threadIdx.y;
  #pragma unroll
  for (int i = 0; i < 4; i++){
    int r = r0 + ty + i * 8;
    t[ty + i * 8][tx] = src[eo + (size_t)r * C + c0 + tx];
  }
  __syncthreads();
  #pragma unroll
  for (int i = 0; i < 4; i++){
    int c = c0 + ty + i * 8;
    dst[eo + (size_t)c * R + r0 + tx] = f2b(t[tx][ty + i * 8]);
  }
}

// ---------- gating ----------
__global__ __launch_bounds__(256) void gating_kernel(const float* __restrict__ x,
                                                     const float* __restrict__ nz,
                                                     const float* __restrict__ wg,
                                                     const float* __restrict__ wn,
                                                     int* __restrict__ counts,
                                                     int4* __restrict__ rowinfo,
                                                     float* __restrict__ loadrow){
  __shared__ float wls[1024 * 16];   // [d][0..7]=gate, [d][8..15]=noise
  int tid = threadIdx.x;
  for (int i = 0; i < 64; i++){
    int idx = i * 256 + tid;
    int d = idx >> 4, c = idx & 15;
    wls[idx] = (c < 8) ? wg[d * 8 + c] : wn[d * 8 + (c - 8)];
  }
  __syncthreads();
  int w = tid >> 6, lane = tid & 63;
  int row = blockIdx.x * 4 + w;
  float ag[8], an[8];
  #pragma unroll
  for (int e = 0; e < 8; e++){ ag[e] = 0.f; an[e] = 0.f; }
  for (int c = 0; c < 16; c++){
    int d = c * 64 + lane;
    float xv = x[(size_t)row * 1024 + d];
    const float* wp = &wls[d * 16];
    #pragma unroll
    for (int e = 0; e < 8; e++){
      ag[e] = fmaf(xv, wp[e], ag[e]);
      an[e] = fmaf(xv, wp[8 + e], an[e]);
    }
  }
  #pragma unroll
  for (int off = 32; off >= 1; off >>= 1){
    #pragma unroll
    for (int e = 0; e < 8; e++){
      ag[e] += __shfl_xor(ag[e], off, 64);
      an[e] += __shfl_xor(an[e], off, 64);
    }
  }
  if (lane == 0){
    float clean[8], sd[8], noisy[8];
    #pragma unroll
    for (int e = 0; e < 8; e++){
      clean[e] = ag[e];
      float v = an[e];
      float sp = fmaxf(v, 0.f) + log1pf(expf(-fabsf(v)));   // softplus
      sd[e] = sp + 0.01f;
      noisy[e] = clean[e] + nz[row * 8 + e] * sd[e];
    }
    int i0 = 0, i1 = -1, i2 = -1;
    float b0 = -3.4e38f, b1v = -3.4e38f, b2v = -3.4e38f;
    #pragma unroll
    for (int j = 0; j < 8; j++){
      float t = noisy[j];
      if (t > b0){ b2v = b1v; i2 = i1; b1v = b0; i1 = i0; b0 = t; i0 = j; }
      else if (t > b1v){ b2v = b1v; i2 = i1; b1v = t; i1 = j; }
      else if (t > b2v){ b2v = t; i2 = j; }
    }
    float eg = expf(b1v - b0);
    float g0 = 1.f / (1.f + eg), g1 = eg / (1.f + eg);
    rowinfo[row] = make_int4(i0, i1, __float_as_int(g0), __float_as_int(g1));
    atomicAdd(&counts[i0], 1);
    atomicAdd(&counts[i1], 1);
    float thr_in = b2v, thr_out = b1v;
    #pragma unroll
    for (int e = 0; e < 8; e++){
      bool isin = noisy[e] > thr_in;
      float thr = isin ? thr_in : thr_out;
      float z = (clean[e] - thr) / sd[e];
      loadrow[row * 8 + e] = 0.5f * (1.f + erff(z * 0.70710678118654752f));
    }
  }
}

// ---------- scan ----------
__global__ void scan_kernel(const int* __restrict__ counts, int* __restrict__ offs){
  if (threadIdx.x == 0){
    int s = 0;
    for (int e = 0; e < 8; e++){ offs[e] = s; s += counts[e]; }
  }
}

// ---------- fill dispatch lists ----------
__global__ __launch_bounds__(256) void fill_kernel(const int4* __restrict__ rowinfo,
                                                   const int* __restrict__ offs,
                                                   int* __restrict__ cnt2,
                                                   int* __restrict__ tok,
                                                   int* __restrict__ slot_of){
  int r = blockIdx.x * 256 + threadIdx.x;
  int4 ri = rowinfo[r];
  int p0 = atomicAdd(&cnt2[ri.x], 1);
  int s0 = offs[ri.x] + p0;
  tok[s0] = r; slot_of[2 * r] = s0;
  int p1 = atomicAdd(&cnt2[ri.y], 1);
  int s1 = offs[ri.y] + p1;
  tok[s1] = r; slot_of[2 * r + 1] = s1;
}

// ---------- grouped GEMM layer 1: h = relu(X_e @ W1_e + b1_e) ----------
__global__ __launch_bounds__(256) void ffn1_kernel(const u16* __restrict__ xb,
                                                   const u16* __restrict__ w1t,
                                                   const float* __restrict__ b1,
                                                   u16* __restrict__ h_buf,
                                                   const int* __restrict__ counts,
                                                   const int* __restrict__ offs,
                                                   const int* __restrict__ tok){
  int e = blockIdx.z;
  int cnt = counts[e];
  int tm = blockIdx.x;
  if (tm * 128 >= cnt) return;
  int tn = blockIdx.y;
  __shared__ u16 Al[128 * 64];
  __shared__ u16 Bl[128 * 64];
  int tid = threadIdx.x;
  int lane = tid & 63;
  int w = tid >> 6, wm = w >> 1, wn = w & 1;
  int off_e = offs[e];
  const u16* bbase = w1t + ((size_t)e << 22) + ((size_t)(tn * 128) << 10);
  const u16* asrc[4];
  const u16* bsrc[4];
  int lbase[4];
  #pragma unroll
  for (int i = 0; i < 4; i++){
    int slot = i * 256 + tid;
    int rl = slot >> 3;
    int c8 = slot & 7;
    int r = tm * 128 + rl;
    int rg = tok[off_e + ((r < cnt) ? r : (cnt - 1))];
    asrc[i] = xb + ((size_t)rg << 10) + c8 * 8;
    bsrc[i] = bbase + ((size_t)rl << 10) + c8 * 8;
    lbase[i] = (i * 256 + (tid & ~63)) * 8;
  }
  f32x4 acc[4][4];
  #pragma unroll
  for (int a_ = 0; a_ < 4; a_++)
    #pragma unroll
    for (int b_ = 0; b_ < 4; b_++) acc[a_][b_] = (f32x4){0.f, 0.f, 0.f, 0.f};
  int lm = lane & 15, lk = (lane >> 4) * 8;
  for (int k0 = 0; k0 < 1024; k0 += 64){
    #pragma unroll
    for (int i = 0; i < 4; i++){
      gload16(asrc[i] + k0, &Al[lbase[i]]);
      gload16(bsrc[i] + k0, &Bl[lbase[i]]);
    }
    __syncthreads();
    #pragma unroll
    for (int kw = 0; kw < 2; kw++){
      int kk = kw * 32 + lk;
      short8 af[4], bfr[4];
      #pragma unroll
      for (int im = 0; im < 4; im++) af[im] = *(const short8*)&Al[(wm * 64 + im * 16 + lm) * 64 + kk];
      #pragma unroll
      for (int in_ = 0; in_ < 4; in_++) bfr[in_] = *(const short8*)&Bl[(wn * 64 + in_ * 16 + lm) * 64 + kk];
      #pragma unroll
      for (int im = 0; im < 4; im++)
        #pragma unroll
        for (int in_ = 0; in_ < 4; in_++)
          acc[im][in_] = __builtin_amdgcn_mfma_f32_16x16x32_bf16(af[im], bfr[in_], acc[im][in_], 0, 0, 0);
    }
    __syncthreads();
  }
  int lr = (lane >> 4) * 4;
  #pragma unroll
  for (int in_ = 0; in_ < 4; in_++){
    int hc = tn * 128 + wn * 64 + in_ * 16 + lm;
    float bias = b1[(e << 12) + hc];
    #pragma unroll
    for (int im = 0; im < 4; im++){
      int rl = wm * 64 + im * 16 + lr;
      #pragma unroll
      for (int q = 0; q < 4; q++){
        int r = tm * 128 + rl + q;
        if (r < cnt){
          float v = acc[im][in_][q] + bias;
          h_buf[((size_t)(off_e + r) << 12) + hc] = f2b(fmaxf(v, 0.f));
        }
      }
    }
  }
}

// ---------- grouped GEMM layer 2: out = h @ W2_e + b2_e ----------
__global__ __launch_bounds__(256) void ffn2_kernel(const u16* __restrict__ h_buf,
                                                   const u16* __restrict__ w2t,
                                                   const float* __restrict__ b2,
                                                   u16* __restrict__ out_buf,
                                                   const int* __restrict__ counts,
                                                   const int* __restrict__ offs){
  int e = blockIdx.z;
  int cnt = counts[e];
  int tm = blockIdx.x;
  if (tm * 128 >= cnt) return;
  int tn = blockIdx.y;
  __shared__ u16 Al[128 * 64];
  __shared__ u16 Bl[128 * 64];
  int tid = threadIdx.x;
  int lane = tid & 63;
  int w = tid >> 6, wm = w >> 1, wn = w & 1;
  int off_e = offs[e];
  const u16* bbase = w2t + ((size_t)e << 22) + ((size_t)(tn * 128) << 12);
  const u16* asrc[4];
  const u16* bsrc[4];
  int lbase[4];
  #pragma unroll
  for (int i = 0; i < 4; i++){
    int slot = i * 256 + tid;
    int rl = slot >> 3;
    int c8 = slot & 7;
    int r = tm * 128 + rl;
    int ra = off_e + ((r < cnt) ? r : (cnt - 1));
    asrc[i] = h_buf + ((size_t)ra << 12) + c8 * 8;
    bsrc[i] = bbase + ((size_t)rl << 12) + c8 * 8;
    lbase[i] = (i * 256 + (tid & ~63)) * 8;
  }
  f32x4 acc[4][4];
  #pragma unroll
  for (int a_ = 0; a_ < 4; a_++)
    #pragma unroll
    for (int b_ = 0; b_ < 4; b_++) acc[a_][b_] = (f32x4){0.f, 0.f, 0.f, 0.f};
  int lm = lane & 15, lk = (lane >> 4) * 8;
  for (int k0 = 0; k0 < 4096; k0 += 64){
    #pragma unroll
    for (int i = 0; i < 4; i++){
      gload16(asrc[i] + k0, &Al[lbase[i]]);
      gload16(bsrc[i] + k0, &Bl[lbase[i]]);
    }
    __syncthreads();
    #pragma unroll
    for (int kw = 0; kw < 2; kw++){
      int kk = kw * 32 + lk;
      short8 af[4], bfr[4];
      #pragma unroll
      for (int im = 0; im < 4; im++) af[im] = *(const short8*)&Al[(wm * 64 + im * 16 + lm) * 64 + kk];
      #pragma unroll
      for (int in_ = 0; in_ < 4; in_++) bfr[in_] = *(const short8*)&Bl[(wn * 64 + in_ * 16 + lm) * 64 + kk];
      #pragma unroll
      for (int im = 0; im < 4; im++)
        #pragma unroll
        for (int in_ = 0; in_ < 4; in_++)
          acc[im][in_] = __builtin_amdgcn_mfma_f32_16x16x32_bf16(af[im], bfr[in_], acc[im][in_], 0, 0, 0);
    }
    __syncthreads();
  }
  int lr = (lane >> 4) * 4;
  #pragma unroll
  for (int in_ = 0; in_ < 4; in_++){
    int dc = tn * 128 + wn * 64 + in_ * 16 + lm;
    float bias = b2[(e << 10) + dc];
    #pragma unroll
    for (int im = 0; im < 4; im++){
      int rl = wm * 64 + im * 16 + lr;
      #pragma unroll
      for (int q = 0; q < 4; q++){
        int r = tm * 128 + rl + q;
        if (r < cnt){
          float v = acc[im][in_][q] + bias;
          out_buf[((size_t)(off_e + r) << 10) + dc] = f2b(v);
        }
      }
    }
  }
}

// ---------- combine: y = g0*out[s0] + g1*out[s1] ----------
__global__ __launch_bounds__(256) void combine_kernel(const u16* __restrict__ out_buf,
                                                      const int4* __restrict__ rowinfo,
                                                      const int* __restrict__ slot_of,
                                                      float* __restrict__ y){
  int g = blockIdx.x * 256 + threadIdx.x;
  int row = g >> 8;
  int c4 = (g & 255) * 4;
  int4 ri = rowinfo[row];
  float g0 = __int_as_float(ri.z), g1 = __int_as_float(ri.w);
  int s0 = slot_of[2 * row], s1 = slot_of[2 * row + 1];
  u16x4 a = *(const u16x4*)&out_buf[((size_t)s0 << 10) + c4];
  u16x4 b = *(const u16x4*)&out_buf[((size_t)s1 << 10) + c4];
  float4 o;
  o.x = g0 * b2f(a.x) + g1 * b2f(b.x);
  o.y = g0 * b2f(a.y) + g1 * b2f(b.y);
  o.z = g0 * b2f(a.z) + g1 * b2f(b.z);
  o.w = g0 * b2f(a.w) + g1 * b2f(b.w);
  *(float4*)&y[(size_t)row * 1024 + c4] = o;
}

// ---------- loss ----------
__global__ __launch_bounds__(256) void loss_kernel(const int4* __restrict__ rowinfo,
                                                   const float* __restrict__ loadrow,
                                                   float* __restrict__ out_loss){
  __shared__ float part[16][256];
  int tid = threadIdx.x;
  float li[8], lo[8];
  #pragma unroll
  for (int e = 0; e < 8; e++){ li[e] = 0.f; lo[e] = 0.f; }
  for (int r = tid; r < 8192; r += 256){
    int4 ri = rowinfo[r];
    float g0 = __int_as_float(ri.z), g1 = __int_as_float(ri.w);
    #pragma unroll
    for (int e = 0; e < 8; e++){
      li[e] += ((ri.x == e) ? g0 : 0.f) + ((ri.y == e) ? g1 : 0.f);
      lo[e] += loadrow[r * 8 + e];
    }
  }
  #pragma unroll
  for (int e = 0; e < 8; e++){ part[e][tid] = li[e]; part[8 + e][tid] = lo[e]; }
  __syncthreads();
  if (tid < 16){
    float s = 0.f;
    for (int j = 0; j < 256; j++) s += part[tid][j];
    part[tid][0] = s;
  }
  __syncthreads();
  if (tid == 0){
    float mi = 0.f, ml = 0.f;
    for (int e = 0; e < 8; e++){ mi += part[e][0]; ml += part[8 + e][0]; }
    mi *= 0.125f; ml *= 0.125f;
    float vi = 0.f, vl = 0.f;
    for (int e = 0; e < 8; e++){
      float di = part[e][0] - mi; vi += di * di;
      float dl = part[8 + e][0] - ml; vl += dl * dl;
    }
    vi /= 7.f; vl /= 7.f;
    float cvi = vi / (mi * mi + 1e-10f);
    float cvl = vl / (ml * ml + 1e-10f);
    out_loss[0] = 0.01f * (cvi + cvl);
  }
}

// ---------- launch ----------
extern "C" void kernel_launch(void* const* d_in, const int* in_sizes, int n_in,
                              void* d_out, int out_size, void* d_ws, size_t ws_size,
                              hipStream_t stream){
  const float* x  = (const float*)d_in[0];
  const float* nz = (const float*)d_in[1];
  const float* wg = (const float*)d_in[2];
  const float* wn = (const float*)d_in[3];
  const float* W1 = (const float*)d_in[4];
  const float* b1 = (const float*)d_in[5];
  const float* W2 = (const float*)d_in[6];
  const float* b2 = (const float*)d_in[7];
  float* y = (float*)d_out;
  float* loss = y + (size_t)8192 * 1024;

  char* ws = (char*)d_ws;
  size_t o = 0;
  auto alloc = [&](size_t bytes){ size_t r = o; o += (bytes + 255) & ~(size_t)255; return r; };
  int*  counts  = (int*)(ws + alloc(64));
  int*  cnt2    = (int*)(ws + alloc(64));
  int*  offs    = (int*)(ws + alloc(64));
  int4* rowinfo = (int4*)(ws + alloc((size_t)8192 * 16));
  int*  slot_of = (int*)(ws + alloc((size_t)16384 * 4));
  int*  tok     = (int*)(ws + alloc((size_t)16384 * 4));
  float* loadrow = (float*)(ws + alloc((size_t)8192 * 8 * 4));
  u16*  xb      = (u16*)(ws + alloc((size_t)8192 * 1024 * 2));
  u16*  w1t     = (u16*)(ws + alloc((size_t)8 * 1024 * 4096 * 2));
  u16*  w2t     = (u16*)(ws + alloc((size_t)8 * 1024 * 4096 * 2));
  u16*  h_buf   = (u16*)(ws + alloc((size_t)16384 * 4096 * 2));
  u16*  out_buf = (u16*)(ws + alloc((size_t)16384 * 1024 * 2));
  if (o > ws_size) return;  // insufficient workspace -> visible as absmax fail

  hipMemsetAsync(ws, 0, 768, stream);  // counts, cnt2, offs

  convert_x_kernel<<<4096, 256, 0, stream>>>(x, xb);
  transpose_cvt_kernel<<<dim3(128, 32, 8), dim3(32, 8), 0, stream>>>(W1, w1t, 1024, 4096);
  transpose_cvt_kernel<<<dim3(32, 128, 8), dim3(32, 8), 0, stream>>>(W2, w2t, 4096, 1024);
  gating_kernel<<<2048, 256, 0, stream>>>(x, nz, wg, wn, counts, rowinfo, loadrow);
  scan_kernel<<<1, 64, 0, stream>>>(counts, offs);
  fill_kernel<<<32, 256, 0, stream>>>(rowinfo, offs, cnt2, tok, slot_of);
  ffn1_kernel<<<dim3(64, 32, 8), 256, 0, stream>>>(xb, w1t, b1, h_buf, counts, offs, tok);
  ffn2_kernel<<<dim3(64, 8, 8), 256, 0, stream>>>(h_buf, w2t, b2, out_buf, counts, offs);
  combine_kernel<<<8192, 256, 0, stream>>>(out_buf, rowinfo, slot_of, y);
  loss_kernel<<<1, 256, 0, stream>>>(rowinfo, loadrow, loss);
}

// Round 2
// 1005.938 us; speedup vs baseline: 1.3749x; 1.3749x over previous
//
#include <hip/hip_runtime.h>

typedef unsigned short u16;
typedef unsigned int u32;
typedef __attribute__((ext_vector_type(4))) float f32x4;
typedef __attribute__((ext_vector_type(8))) short short8;
typedef __attribute__((ext_vector_type(4))) unsigned short u16x4;

// ---------- helpers ----------
__device__ __forceinline__ u16 f2b(float f){
  u32 u = __float_as_uint(f);
  u = (u + 0x7FFFu + ((u >> 16) & 1u)) >> 16;   // RNE
  return (u16)u;
}
__device__ __forceinline__ float b2f(u16 h){ return __uint_as_float(((u32)h) << 16); }

__device__ __forceinline__ void gload16(const void* g, void* l){
  __builtin_amdgcn_global_load_lds((__attribute__((address_space(1))) void*)(g),
                                   (__attribute__((address_space(3))) void*)(l), 16, 0, 0);
}

// ---------- x f32 -> bf16 ----------
__global__ __launch_bounds__(256) void convert_x_kernel(const float* __restrict__ x,
                                                        u16* __restrict__ xb){
  int g = blockIdx.x * 256 + threadIdx.x;
  const float4* p = (const float4*)x + (size_t)g * 2;
  float4 a = p[0], b = p[1];
  u16x4 o0 = { f2b(a.x), f2b(a.y), f2b(a.z), f2b(a.w) };
  u16x4 o1 = { f2b(b.x), f2b(b.y), f2b(b.z), f2b(b.w) };
  ((u16x4*)xb)[(size_t)g * 2]     = o0;
  ((u16x4*)xb)[(size_t)g * 2 + 1] = o1;
}

// ---------- W f32 [R][C] -> bf16 transposed [C][R], per expert ----------
__global__ __launch_bounds__(256) void transpose_cvt_kernel(const float* __restrict__ src,
                                                            u16* __restrict__ dst,
                                                            int R, int C){
  __shared__ float t[32][33];
  int e = blockIdx.z;
  size_t eo = (size_t)R * C * e;
  int c0 = blockIdx.x * 32, r0 = blockIdx.y * 32;
  int tx = threadIdx.x, ty = threadIdx.y;
  #pragma unroll
  for (int i = 0; i < 4; i++){
    int r = r0 + ty + i * 8;
    t[ty + i * 8][tx] = src[eo + (size_t)r * C + c0 + tx];
  }
  __syncthreads();
  #pragma unroll
  for (int i = 0; i < 4; i++){
    int c = c0 + ty + i * 8;
    dst[eo + (size_t)c * R + r0 + tx] = f2b(t[tx][ty + i * 8]);
  }
}

// ---------- gating ----------
__global__ __launch_bounds__(256) void gating_kernel(const float* __restrict__ x,
                                                     const float* __restrict__ nz,
                                                     const float* __restrict__ wg,
                                                     const float* __restrict__ wn,
                                                     int* __restrict__ counts,
                                                     int4* __restrict__ rowinfo,
                                                     float* __restrict__ loadrow){
  __shared__ float wls[1024 * 16];
  int tid = threadIdx.x;
  for (int i = 0; i < 64; i++){
    int idx = i * 256 + tid;
    int d = idx >> 4, c = idx & 15;
    wls[idx] = (c < 8) ? wg[d * 8 + c] : wn[d * 8 + (c - 8)];
  }
  __syncthreads();
  int w = tid >> 6, lane = tid & 63;
  int row = blockIdx.x * 4 + w;
  float ag[8], an[8];
  #pragma unroll
  for (int e = 0; e < 8; e++){ ag[e] = 0.f; an[e] = 0.f; }
  for (int c = 0; c < 16; c++){
    int d = c * 64 + lane;
    float xv = x[(size_t)row * 1024 + d];
    const float* wp = &wls[d * 16];
    #pragma unroll
    for (int e = 0; e < 8; e++){
      ag[e] = fmaf(xv, wp[e], ag[e]);
      an[e] = fmaf(xv, wp[8 + e], an[e]);
    }
  }
  #pragma unroll
  for (int off = 32; off >= 1; off >>= 1){
    #pragma unroll
    for (int e = 0; e < 8; e++){
      ag[e] += __shfl_xor(ag[e], off, 64);
      an[e] += __shfl_xor(an[e], off, 64);
    }
  }
  if (lane == 0){
    float clean[8], sd[8], noisy[8];
    #pragma unroll
    for (int e = 0; e < 8; e++){
      clean[e] = ag[e];
      float v = an[e];
      float sp = fmaxf(v, 0.f) + log1pf(expf(-fabsf(v)));
      sd[e] = sp + 0.01f;
      noisy[e] = clean[e] + nz[row * 8 + e] * sd[e];
    }
    int i0 = 0, i1 = -1;
    float b0 = -3.4e38f, b1v = -3.4e38f, b2v = -3.4e38f;
    #pragma unroll
    for (int j = 0; j < 8; j++){
      float t = noisy[j];
      if (t > b0){ b2v = b1v; b1v = b0; i1 = i0; b0 = t; i0 = j; }
      else if (t > b1v){ b2v = b1v; b1v = t; i1 = j; }
      else if (t > b2v){ b2v = t; }
    }
    float eg = expf(b1v - b0);
    float g0 = 1.f / (1.f + eg), g1 = eg / (1.f + eg);
    rowinfo[row] = make_int4(i0, i1, __float_as_int(g0), __float_as_int(g1));
    atomicAdd(&counts[i0], 1);
    atomicAdd(&counts[i1], 1);
    float thr_in = b2v, thr_out = b1v;
    #pragma unroll
    for (int e = 0; e < 8; e++){
      bool isin = noisy[e] > thr_in;
      float thr = isin ? thr_in : thr_out;
      float z = (clean[e] - thr) / sd[e];
      loadrow[row * 8 + e] = 0.5f * (1.f + erff(z * 0.70710678118654752f));
    }
  }
}

// ---------- scan + block table ----------
__global__ void scan_kernel(const int* __restrict__ counts, int* __restrict__ offs,
                            int* __restrict__ btab){
  if (threadIdx.x == 0){
    int s = 0, nb = 0;
    for (int e = 0; e < 8; e++){
      offs[e] = s;
      int c = counts[e]; s += c;
      int nbe = (c + 127) >> 7;
      for (int t = 0; t < nbe; t++) btab[nb++] = (e << 16) | t;
    }
    offs[15] = nb;
  }
}

// ---------- fill dispatch lists ----------
__global__ __launch_bounds__(256) void fill_kernel(const int4* __restrict__ rowinfo,
                                                   const int* __restrict__ offs,
                                                   int* __restrict__ cnt2,
                                                   int* __restrict__ tok,
                                                   int* __restrict__ slot_of){
  int r = blockIdx.x * 256 + threadIdx.x;
  int4 ri = rowinfo[r];
  int p0 = atomicAdd(&cnt2[ri.x], 1);
  int s0 = offs[ri.x] + p0;
  tok[s0] = r; slot_of[2 * r] = s0;
  int p1 = atomicAdd(&cnt2[ri.y], 1);
  int s1 = offs[ri.y] + p1;
  tok[s1] = r; slot_of[2 * r + 1] = s1;
}

// ---------- grouped GEMM, 2-phase double-buffered, swizzled LDS ----------
// KDIM: K depth; OSTR: output row stride (= #cols); GATHER: A rows via tok[]
template<int KDIM, int OSTR, bool GATHER, bool RELU>
__global__ __launch_bounds__(256) void ffn_kernel(const u16* __restrict__ Ag,
                                                  const u16* __restrict__ Bt,
                                                  const float* __restrict__ bias,
                                                  u16* __restrict__ outp,
                                                  const int* __restrict__ counts,
                                                  const int* __restrict__ offs,
                                                  const int* __restrict__ btab,
                                                  const int* __restrict__ tok){
  // bijective XCD swizzle over the linearized grid (total % 8 == 0: gx=136)
  int gx = gridDim.x;
  int lin = blockIdx.y * gx + blockIdx.x;
  int total = gx * gridDim.y, chunk = total >> 3;
  int swz = (lin & 7) * chunk + (lin >> 3);
  int bx = swz % gx, tn = swz / gx;
  int nblk = offs[15];
  if (bx >= nblk) return;
  int et = btab[bx]; int e = et >> 16, tm = et & 0xffff;
  int cnt = counts[e], off_e = offs[e];

  __shared__ u16 Al[2][128 * 64];
  __shared__ u16 Bl[2][128 * 64];
  int tid = threadIdx.x, lane = tid & 63;
  int w = tid >> 6, wm = w >> 1, wn = w & 1;

  const u16* bbase = Bt + (size_t)e * 4194304 + (size_t)(tn * 128) * KDIM;
  const u16* asrc[4];
  const u16* bsrc[4];
  int lbase[4];
  #pragma unroll
  for (int i = 0; i < 4; i++){
    int slot = i * 256 + tid;
    int rl = slot >> 3;
    int c8 = slot & 7;
    int c8s = c8 ^ (rl & 7);              // source pre-swizzle (rule #21)
    int r = tm * 128 + rl;
    int rc = (r < cnt) ? r : (cnt - 1);
    size_t arow;
    if (GATHER) arow = (size_t)tok[off_e + rc] * KDIM;
    else        arow = (size_t)(off_e + rc) * KDIM;
    asrc[i] = Ag + arow + c8s * 8;
    bsrc[i] = bbase + (size_t)rl * KDIM + c8s * 8;
    lbase[i] = (i * 256 + (tid & ~63)) * 8;   // wave-uniform linear LDS dest
  }

  f32x4 acc[4][4];
  #pragma unroll
  for (int a_ = 0; a_ < 4; a_++)
    #pragma unroll
    for (int b_ = 0; b_ < 4; b_++) acc[a_][b_] = (f32x4){0.f, 0.f, 0.f, 0.f};

  auto stage = [&](int buf, int k0){
    #pragma unroll
    for (int i = 0; i < 4; i++){
      gload16(asrc[i] + k0, &Al[buf][lbase[i]]);
      gload16(bsrc[i] + k0, &Bl[buf][lbase[i]]);
    }
  };

  int lm = lane & 15, lk = (lane >> 4) * 8;
  int sx = (lm & 7) << 3;                 // read-side XOR (u16 units), row&7 == lm&7
  constexpr int NT = KDIM / 64;

  stage(0, 0);
  __syncthreads();
  int cur = 0;
  for (int t = 0; t < NT; ++t){
    if (t + 1 < NT) stage(cur ^ 1, (t + 1) * 64);
    #pragma unroll
    for (int kw = 0; kw < 2; kw++){
      int kk = kw * 32 + lk;
      short8 af[4], bfr[4];
      #pragma unroll
      for (int im = 0; im < 4; im++)
        af[im] = *(const short8*)&Al[cur][(((wm * 64 + im * 16 + lm) * 64 + kk)) ^ sx];
      #pragma unroll
      for (int in_ = 0; in_ < 4; in_++)
        bfr[in_] = *(const short8*)&Bl[cur][(((wn * 64 + in_ * 16 + lm) * 64 + kk)) ^ sx];
      #pragma unroll
      for (int im = 0; im < 4; im++)
        #pragma unroll
        for (int in_ = 0; in_ < 4; in_++)
          acc[im][in_] = __builtin_amdgcn_mfma_f32_16x16x32_bf16(af[im], bfr[in_], acc[im][in_], 0, 0, 0);
    }
    __syncthreads();
    cur ^= 1;
  }

  int lr = (lane >> 4) * 4;
  #pragma unroll
  for (int in_ = 0; in_ < 4; in_++){
    int col = tn * 128 + wn * 64 + in_ * 16 + lm;
    float bv = bias[e * OSTR + col];
    #pragma unroll
    for (int im = 0; im < 4; im++){
      int rl = wm * 64 + im * 16 + lr;
      #pragma unroll
      for (int q = 0; q < 4; q++){
        int r = tm * 128 + rl + q;
        if (r < cnt){
          float v = acc[im][in_][q] + bv;
          if (RELU) v = fmaxf(v, 0.f);
          outp[((size_t)(off_e + r)) * OSTR + col] = f2b(v);
        }
      }
    }
  }
}

// ---------- combine: y = g0*out[s0] + g1*out[s1] ----------
__global__ __launch_bounds__(256) void combine_kernel(const u16* __restrict__ out_buf,
                                                      const int4* __restrict__ rowinfo,
                                                      const int* __restrict__ slot_of,
                                                      float* __restrict__ y){
  int g = blockIdx.x * 256 + threadIdx.x;
  int row = g >> 8;
  int c4 = (g & 255) * 4;
  int4 ri = rowinfo[row];
  float g0 = __int_as_float(ri.z), g1 = __int_as_float(ri.w);
  int s0 = slot_of[2 * row], s1 = slot_of[2 * row + 1];
  u16x4 a = *(const u16x4*)&out_buf[((size_t)s0 << 10) + c4];
  u16x4 b = *(const u16x4*)&out_buf[((size_t)s1 << 10) + c4];
  float4 o;
  o.x = g0 * b2f(a.x) + g1 * b2f(b.x);
  o.y = g0 * b2f(a.y) + g1 * b2f(b.y);
  o.z = g0 * b2f(a.z) + g1 * b2f(b.z);
  o.w = g0 * b2f(a.w) + g1 * b2f(b.w);
  *(float4*)&y[(size_t)row * 1024 + c4] = o;
}

// ---------- loss ----------
__global__ __launch_bounds__(256) void loss_kernel(const int4* __restrict__ rowinfo,
                                                   const float* __restrict__ loadrow,
                                                   float* __restrict__ out_loss){
  __shared__ float part[16][256];
  int tid = threadIdx.x;
  float li[8], lo[8];
  #pragma unroll
  for (int e = 0; e < 8; e++){ li[e] = 0.f; lo[e] = 0.f; }
  for (int r = tid; r < 8192; r += 256){
    int4 ri = rowinfo[r];
    float g0 = __int_as_float(ri.z), g1 = __int_as_float(ri.w);
    #pragma unroll
    for (int e = 0; e < 8; e++){
      li[e] += ((ri.x == e) ? g0 : 0.f) + ((ri.y == e) ? g1 : 0.f);
      lo[e] += loadrow[r * 8 + e];
    }
  }
  #pragma unroll
  for (int e = 0; e < 8; e++){ part[e][tid] = li[e]; part[8 + e][tid] = lo[e]; }
  __syncthreads();
  if (tid < 16){
    float s = 0.f;
    for (int j = 0; j < 256; j++) s += part[tid][j];
    part[tid][0] = s;
  }
  __syncthreads();
  if (tid == 0){
    float mi = 0.f, ml = 0.f;
    for (int e = 0; e < 8; e++){ mi += part[e][0]; ml += part[8 + e][0]; }
    mi *= 0.125f; ml *= 0.125f;
    float vi = 0.f, vl = 0.f;
    for (int e = 0; e < 8; e++){
      float di = part[e][0] - mi; vi += di * di;
      float dl = part[8 + e][0] - ml; vl += dl * dl;
    }
    vi /= 7.f; vl /= 7.f;
    float cvi = vi / (mi * mi + 1e-10f);
    float cvl = vl / (ml * ml + 1e-10f);
    out_loss[0] = 0.01f * (cvi + cvl);
  }
}

// ---------- launch ----------
extern "C" void kernel_launch(void* const* d_in, const int* in_sizes, int n_in,
                              void* d_out, int out_size, void* d_ws, size_t ws_size,
                              hipStream_t stream){
  const float* x  = (const float*)d_in[0];
  const float* nz = (const float*)d_in[1];
  const float* wg = (const float*)d_in[2];
  const float* wn = (const float*)d_in[3];
  const float* W1 = (const float*)d_in[4];
  const float* b1 = (const float*)d_in[5];
  const float* W2 = (const float*)d_in[6];
  const float* b2 = (const float*)d_in[7];
  float* y = (float*)d_out;
  float* loss = y + (size_t)8192 * 1024;

  char* ws = (char*)d_ws;
  size_t o = 0;
  auto alloc = [&](size_t bytes){ size_t r = o; o += (bytes + 255) & ~(size_t)255; return r; };
  int*  counts  = (int*)(ws + alloc(64));
  int*  cnt2    = (int*)(ws + alloc(64));
  int*  offs    = (int*)(ws + alloc(64));
  int*  btab    = (int*)(ws + alloc(1024));
  int4* rowinfo = (int4*)(ws + alloc((size_t)8192 * 16));
  int*  slot_of = (int*)(ws + alloc((size_t)16384 * 4));
  int*  tok     = (int*)(ws + alloc((size_t)16384 * 4));
  float* loadrow = (float*)(ws + alloc((size_t)8192 * 8 * 4));
  u16*  xb      = (u16*)(ws + alloc((size_t)8192 * 1024 * 2));
  u16*  w1t     = (u16*)(ws + alloc((size_t)8 * 1024 * 4096 * 2));
  u16*  w2t     = (u16*)(ws + alloc((size_t)8 * 1024 * 4096 * 2));
  u16*  h_buf   = (u16*)(ws + alloc((size_t)16384 * 4096 * 2));
  u16*  out_buf = (u16*)(ws + alloc((size_t)16384 * 1024 * 2));
  if (o > ws_size) return;

  hipMemsetAsync(ws, 0, 768, stream);  // counts, cnt2, offs (+nblk slot)

  convert_x_kernel<<<4096, 256, 0, stream>>>(x, xb);
  transpose_cvt_kernel<<<dim3(128, 32, 8), dim3(32, 8), 0, stream>>>(W1, w1t, 1024, 4096);
  transpose_cvt_kernel<<<dim3(32, 128, 8), dim3(32, 8), 0, stream>>>(W2, w2t, 4096, 1024);
  gating_kernel<<<2048, 256, 0, stream>>>(x, nz, wg, wn, counts, rowinfo, loadrow);
  scan_kernel<<<1, 64, 0, stream>>>(counts, offs, btab);
  fill_kernel<<<32, 256, 0, stream>>>(rowinfo, offs, cnt2, tok, slot_of);
  ffn_kernel<1024, 4096, true,  true ><<<dim3(136, 32), 256, 0, stream>>>(xb, w1t, b1, h_buf, counts, offs, btab, tok);
  ffn_kernel<4096, 1024, false, false><<<dim3(136, 8),  256, 0, stream>>>(h_buf, w2t, b2, out_buf, counts, offs, btab, tok);
  combine_kernel<<<8192, 256, 0, stream>>>(out_buf, rowinfo, slot_of, y);
  loss_kernel<<<1, 256, 0, stream>>>(rowinfo, loadrow, loss);
}

// Round 4
// 873.905 us; speedup vs baseline: 1.5826x; 1.1511x over previous
//
#include <hip/hip_runtime.h>

typedef unsigned short u16;
typedef unsigned int u32;
typedef __attribute__((ext_vector_type(4))) float f32x4;
typedef __attribute__((ext_vector_type(8))) short short8;
typedef __attribute__((ext_vector_type(4))) unsigned short u16x4;

#define BARR __builtin_amdgcn_s_barrier()
#define VM2  asm volatile("s_waitcnt vmcnt(2)" ::: "memory")
#define VM0  asm volatile("s_waitcnt vmcnt(0)" ::: "memory")

// ---------- helpers ----------
__device__ __forceinline__ u16 f2b(float f){
  u32 u = __float_as_uint(f);
  u = (u + 0x7FFFu + ((u >> 16) & 1u)) >> 16;   // RNE
  return (u16)u;
}
__device__ __forceinline__ float b2f(u16 h){ return __uint_as_float(((u32)h) << 16); }

__device__ __forceinline__ void gload16(const void* g, void* l){
  __builtin_amdgcn_global_load_lds((__attribute__((address_space(1))) void*)(g),
                                   (__attribute__((address_space(3))) void*)(l), 16, 0, 0);
}

// ---------- W f32 [R][C] -> bf16 transposed [C][R], per expert ----------
__global__ __launch_bounds__(256) void transpose_cvt_kernel(const float* __restrict__ src,
                                                            u16* __restrict__ dst,
                                                            int R, int C){
  __shared__ float t[32][33];
  int e = blockIdx.z;
  size_t eo = (size_t)R * C * e;
  int c0 = blockIdx.x * 32, r0 = blockIdx.y * 32;
  int tx = threadIdx.x, ty = threadIdx.y;
  #pragma unroll
  for (int i = 0; i < 4; i++){
    int r = r0 + ty + i * 8;
    t[ty + i * 8][tx] = src[eo + (size_t)r * C + c0 + tx];
  }
  __syncthreads();
  #pragma unroll
  for (int i = 0; i < 4; i++){
    int c = c0 + ty + i * 8;
    dst[eo + (size_t)c * R + r0 + tx] = f2b(t[tx][ty + i * 8]);
  }
}

// ---------- gating (+ fused x->bf16 conversion) ----------
__global__ __launch_bounds__(256) void gating_kernel(const float* __restrict__ x,
                                                     const float* __restrict__ nz,
                                                     const float* __restrict__ wg,
                                                     const float* __restrict__ wn,
                                                     int* __restrict__ counts,
                                                     int4* __restrict__ rowinfo,
                                                     float* __restrict__ loadrow,
                                                     u16* __restrict__ xb){
  __shared__ float wls[1024 * 16];
  int tid = threadIdx.x;
  for (int i = 0; i < 64; i++){
    int idx = i * 256 + tid;
    int d = idx >> 4, c = idx & 15;
    wls[idx] = (c < 8) ? wg[d * 8 + c] : wn[d * 8 + (c - 8)];
  }
  __syncthreads();
  int w = tid >> 6, lane = tid & 63;
  int row = blockIdx.x * 4 + w;
  float ag[8], an[8];
  #pragma unroll
  for (int e = 0; e < 8; e++){ ag[e] = 0.f; an[e] = 0.f; }
  for (int c = 0; c < 16; c++){
    int d = c * 64 + lane;
    float xv = x[(size_t)row * 1024 + d];
    xb[(size_t)row * 1024 + d] = f2b(xv);
    const float* wp = &wls[d * 16];
    #pragma unroll
    for (int e = 0; e < 8; e++){
      ag[e] = fmaf(xv, wp[e], ag[e]);
      an[e] = fmaf(xv, wp[8 + e], an[e]);
    }
  }
  #pragma unroll
  for (int off = 32; off >= 1; off >>= 1){
    #pragma unroll
    for (int e = 0; e < 8; e++){
      ag[e] += __shfl_xor(ag[e], off, 64);
      an[e] += __shfl_xor(an[e], off, 64);
    }
  }
  if (lane == 0){
    float clean[8], sd[8], noisy[8];
    #pragma unroll
    for (int e = 0; e < 8; e++){
      clean[e] = ag[e];
      float v = an[e];
      float sp = fmaxf(v, 0.f) + log1pf(expf(-fabsf(v)));
      sd[e] = sp + 0.01f;
      noisy[e] = clean[e] + nz[row * 8 + e] * sd[e];
    }
    int i0 = 0, i1 = -1;
    float b0 = -3.4e38f, b1v = -3.4e38f, b2v = -3.4e38f;
    #pragma unroll
    for (int j = 0; j < 8; j++){
      float t = noisy[j];
      if (t > b0){ b2v = b1v; b1v = b0; i1 = i0; b0 = t; i0 = j; }
      else if (t > b1v){ b2v = b1v; b1v = t; i1 = j; }
      else if (t > b2v){ b2v = t; }
    }
    float eg = expf(b1v - b0);
    float g0 = 1.f / (1.f + eg), g1 = eg / (1.f + eg);
    rowinfo[row] = make_int4(i0, i1, __float_as_int(g0), __float_as_int(g1));
    atomicAdd(&counts[i0], 1);
    atomicAdd(&counts[i1], 1);
    float thr_in = b2v, thr_out = b1v;
    #pragma unroll
    for (int e = 0; e < 8; e++){
      bool isin = noisy[e] > thr_in;
      float thr = isin ? thr_in : thr_out;
      float z = (clean[e] - thr) / sd[e];
      loadrow[row * 8 + e] = 0.5f * (1.f + erff(z * 0.70710678118654752f));
    }
  }
}

// ---------- scan + block table (256-row blocks) ----------
__global__ void scan_kernel(const int* __restrict__ counts, int* __restrict__ offs,
                            int* __restrict__ btab){
  if (threadIdx.x == 0){
    int s = 0, nb = 0;
    for (int e = 0; e < 8; e++){
      offs[e] = s;
      int c = counts[e]; s += c;
      int nbe = (c + 255) >> 8;
      for (int t = 0; t < nbe; t++) btab[nb++] = (e << 16) | t;
    }
    offs[15] = nb;
  }
}

// ---------- fill dispatch lists ----------
__global__ __launch_bounds__(256) void fill_kernel(const int4* __restrict__ rowinfo,
                                                   const int* __restrict__ offs,
                                                   int* __restrict__ cnt2,
                                                   int* __restrict__ tok,
                                                   int* __restrict__ slot_of){
  int r = blockIdx.x * 256 + threadIdx.x;
  int4 ri = rowinfo[r];
  int p0 = atomicAdd(&cnt2[ri.x], 1);
  int s0 = offs[ri.x] + p0;
  tok[s0] = r; slot_of[2 * r] = s0;
  int p1 = atomicAdd(&cnt2[ri.y], 1);
  int s1 = offs[ri.y] + p1;
  tok[s1] = r; slot_of[2 * r + 1] = s1;
}

// ---------- grouped GEMM, 256x256 tile, 8-phase counted-vmcnt schedule ----------
// Iter j computes K-tiles 2j (buf0) and 2j+1 (buf1). Steady-state vmcnt ledger:
// at P4's vmcnt(2): outstanding = {A1h0(t1),A1h1(t1),B1h0(t1),B1h1(t1),A0h0(t2)} = 10
//   -> waits to 2, leaving only A0h0(t2): all of buf1/t1 landed before P5 reads it.
// at P8's vmcnt(2): leaves only A1h0(t3): all of buf0/t2 landed before next P1.
// LAST iteration is PEELED (R3 bug: skipped stages shifted the ledger so vmcnt(2)
// left B1h1(t1) un-landed while wn>=2 waves read it): peel keeps P1-P3 stages and
// drains vmcnt(0) before the buf1 quadrants.
template<int KDIM, int OSTR, bool GATHER, bool RELU>
__global__ __launch_bounds__(512, 1) void ffn8_kernel(
    const u16* __restrict__ Ag, const u16* __restrict__ Bt,
    const float* __restrict__ bias, u16* __restrict__ outp,
    const int* __restrict__ counts, const int* __restrict__ offs,
    const int* __restrict__ btab, const int* __restrict__ tok)
{
  constexpr int NT = KDIM / 64;
  constexpr int NITER = NT / 2;
  __shared__ u16 As[2][2][128 * 64];
  __shared__ u16 Bs[2][2][128 * 64];

  int gx = gridDim.x;
  int lin = blockIdx.y * gx + blockIdx.x;
  int total = gx * gridDim.y, chunk = total >> 3;
  int swz = (lin & 7) * chunk + (lin >> 3);       // bijective: total % 8 == 0
  int bx = swz % gx, tn = swz / gx;
  int nblk = offs[15];
  if (bx >= nblk) return;
  int et = btab[bx]; int e = et >> 16, tm = et & 0xffff;
  int cnt = counts[e], off_e = offs[e];

  int tid = threadIdx.x, lane = tid & 63;
  int wid = tid >> 6, wm = wid >> 2, wn = wid & 3;

  // staging source byte offsets (source pre-swizzled; LDS dest linear — rule #21)
  int rl0 = tid >> 3, c8 = tid & 7;
  const char* Abase = (const char*)Ag;
  const char* Bbase = (const char*)(Bt + (size_t)e * 4194304);
  u32 aoff[4], boff[4];
  #pragma unroll
  for (int h = 0; h < 2; h++)
    #pragma unroll
    for (int r = 0; r < 2; r++){
      int rl = h * 128 + r * 64 + rl0;
      int c8s = c8 ^ (rl & 7);
      int rr = tm * 256 + rl;
      int rc = (rr < cnt) ? rr : (cnt - 1);
      size_t arow = GATHER ? (size_t)tok[off_e + rc] : (size_t)(off_e + rc);
      aoff[h * 2 + r] = (u32)(arow * (KDIM * 2) + c8s * 16);
      boff[h * 2 + r] = (u32)((size_t)(tn * 256 + rl) * (KDIM * 2) + c8s * 16);
    }
  int ldst = (tid & ~63) * 8;   // wave-uniform linear LDS dest (elements)

  auto stA = [&](int b, int h, int t){
    const char* s = Abase + (size_t)t * 128;
    gload16(s + aoff[h * 2 + 0], &As[b][h][ldst]);
    gload16(s + aoff[h * 2 + 1], &As[b][h][4096 + ldst]);
  };
  auto stB = [&](int b, int h, int t){
    const char* s = Bbase + (size_t)t * 128;
    gload16(s + boff[h * 2 + 0], &Bs[b][h][ldst]);
    gload16(s + boff[h * 2 + 1], &Bs[b][h][4096 + ldst]);
  };

  int lm = lane & 15, lkb = (lane >> 4) * 8;
  short8 Ar[4][2], Br[2][2][2];
  auto ldA = [&](int b, int rh){
    #pragma unroll
    for (int ii = 0; ii < 4; ii++){
      int rl = rh * 64 + ii * 16 + lm;
      #pragma unroll
      for (int ks = 0; ks < 2; ks++){
        int idx = (rl * 64 + ks * 32 + lkb) ^ ((rl & 7) << 3);
        Ar[ii][ks] = *(const short8*)&As[b][wm][idx];
      }
    }
  };
  auto ldB = [&](int b, int ch){
    #pragma unroll
    for (int jj = 0; jj < 2; jj++){
      int rb = wn * 64 + ch * 32 + jj * 16 + lm;
      int hB = rb >> 7, rl = rb & 127;
      #pragma unroll
      for (int ks = 0; ks < 2; ks++){
        int idx = (rl * 64 + ks * 32 + lkb) ^ ((rl & 7) << 3);
        Br[ch][jj][ks] = *(const short8*)&Bs[b][hB][idx];
      }
    }
  };

  f32x4 acc[8][4];
  #pragma unroll
  for (int i = 0; i < 8; i++)
    #pragma unroll
    for (int j = 0; j < 4; j++) acc[i][j] = (f32x4){0.f, 0.f, 0.f, 0.f};

  auto mfmaQ = [&](int rh, int ch){
    __builtin_amdgcn_s_setprio(1);
    #pragma unroll
    for (int ks = 0; ks < 2; ks++)
      #pragma unroll
      for (int ii = 0; ii < 4; ii++)
        #pragma unroll
        for (int jj = 0; jj < 2; jj++)
          acc[rh * 4 + ii][ch * 2 + jj] = __builtin_amdgcn_mfma_f32_16x16x32_bf16(
              Ar[ii][ks], Br[ch][jj][ks], acc[rh * 4 + ii][ch * 2 + jj], 0, 0, 0);
    __builtin_amdgcn_s_setprio(0);
  };

  // prologue: tile0 all 4 halves -> buf0, tile1 A-h0 -> buf1
  stA(0, 0, 0); stA(0, 1, 0); stB(0, 0, 0); stB(0, 1, 0);
  stA(1, 0, 1);
  VM2; BARR;

  for (int j = 0; j < NITER - 1; ++j){
    int t1 = 2 * j + 1, t2 = 2 * j + 2, t3 = 2 * j + 3;
    // P1
    ldA(0, 0); ldB(0, 0);
    stA(1, 1, t1);
    BARR; mfmaQ(0, 0); BARR;
    // P2
    ldB(0, 1);
    stB(1, 0, t1);
    BARR; mfmaQ(0, 1); BARR;
    // P3
    ldA(0, 1);
    stB(1, 1, t1);
    BARR; mfmaQ(1, 1); BARR;
    // P4 (Br[0] regs still hold buf0 ch0)
    stA(0, 0, t2);
    BARR; mfmaQ(1, 0); VM2; BARR;
    // P5
    ldA(1, 0); ldB(1, 0);
    stA(0, 1, t2);
    BARR; mfmaQ(0, 0); BARR;
    // P6
    ldB(1, 1);
    stB(0, 0, t2);
    BARR; mfmaQ(0, 1); BARR;
    // P7
    ldA(1, 1);
    stB(0, 1, t2);
    BARR; mfmaQ(1, 1); BARR;
    // P8
    stA(1, 0, t3);
    BARR; mfmaQ(1, 0); VM2; BARR;
  }

  { // peeled last iteration: stages only P1-P3 (tile NT-1 -> buf1), full drain at P4
    int t1 = NT - 1;
    ldA(0, 0); ldB(0, 0);
    stA(1, 1, t1);
    BARR; mfmaQ(0, 0); BARR;
    ldB(0, 1);
    stB(1, 0, t1);
    BARR; mfmaQ(0, 1); BARR;
    ldA(0, 1);
    stB(1, 1, t1);
    BARR; mfmaQ(1, 1); BARR;
    mfmaQ(1, 0); VM0; BARR;
    ldA(1, 0); ldB(1, 0);
    BARR; mfmaQ(0, 0); BARR;
    ldB(1, 1);
    BARR; mfmaQ(0, 1); BARR;
    ldA(1, 1);
    BARR; mfmaQ(1, 1); BARR;
    mfmaQ(1, 0);
  }

  // epilogue: C write
  int lr = (lane >> 4) * 4;
  #pragma unroll
  for (int i = 0; i < 8; i++){
    int row_l = wm * 128 + i * 16 + lr;
    #pragma unroll
    for (int jj = 0; jj < 4; jj++){
      int col = tn * 256 + wn * 64 + jj * 16 + lm;
      float bv = bias[e * OSTR + col];
      #pragma unroll
      for (int q = 0; q < 4; q++){
        int r = tm * 256 + row_l + q;
        if (r < cnt){
          float v = acc[i][jj][q] + bv;
          if (RELU) v = fmaxf(v, 0.f);
          outp[(size_t)(off_e + r) * OSTR + col] = f2b(v);
        }
      }
    }
  }
}

// ---------- combine: y = g0*out[s0] + g1*out[s1] ----------
__global__ __launch_bounds__(256) void combine_kernel(const u16* __restrict__ out_buf,
                                                      const int4* __restrict__ rowinfo,
                                                      const int* __restrict__ slot_of,
                                                      float* __restrict__ y){
  int g = blockIdx.x * 256 + threadIdx.x;
  int row = g >> 8;
  int c4 = (g & 255) * 4;
  int4 ri = rowinfo[row];
  float g0 = __int_as_float(ri.z), g1 = __int_as_float(ri.w);
  int s0 = slot_of[2 * row], s1 = slot_of[2 * row + 1];
  u16x4 a = *(const u16x4*)&out_buf[((size_t)s0 << 10) + c4];
  u16x4 b = *(const u16x4*)&out_buf[((size_t)s1 << 10) + c4];
  float4 o;
  o.x = g0 * b2f(a.x) + g1 * b2f(b.x);
  o.y = g0 * b2f(a.y) + g1 * b2f(b.y);
  o.z = g0 * b2f(a.z) + g1 * b2f(b.z);
  o.w = g0 * b2f(a.w) + g1 * b2f(b.w);
  *(float4*)&y[(size_t)row * 1024 + c4] = o;
}

// ---------- loss ----------
__global__ __launch_bounds__(256) void loss_kernel(const int4* __restrict__ rowinfo,
                                                   const float* __restrict__ loadrow,
                                                   float* __restrict__ out_loss){
  __shared__ float part[16][256];
  int tid = threadIdx.x;
  float li[8], lo[8];
  #pragma unroll
  for (int e = 0; e < 8; e++){ li[e] = 0.f; lo[e] = 0.f; }
  for (int r = tid; r < 8192; r += 256){
    int4 ri = rowinfo[r];
    float g0 = __int_as_float(ri.z), g1 = __int_as_float(ri.w);
    #pragma unroll
    for (int e = 0; e < 8; e++){
      li[e] += ((ri.x == e) ? g0 : 0.f) + ((ri.y == e) ? g1 : 0.f);
      lo[e] += loadrow[r * 8 + e];
    }
  }
  #pragma unroll
  for (int e = 0; e < 8; e++){ part[e][tid] = li[e]; part[8 + e][tid] = lo[e]; }
  __syncthreads();
  if (tid < 16){
    float s = 0.f;
    for (int j = 0; j < 256; j++) s += part[tid][j];
    part[tid][0] = s;
  }
  __syncthreads();
  if (tid == 0){
    float mi = 0.f, ml = 0.f;
    for (int e = 0; e < 8; e++){ mi += part[e][0]; ml += part[8 + e][0]; }
    mi *= 0.125f; ml *= 0.125f;
    float vi = 0.f, vl = 0.f;
    for (int e = 0; e < 8; e++){
      float di = part[e][0] - mi; vi += di * di;
      float dl = part[8 + e][0] - ml; vl += dl * dl;
    }
    vi /= 7.f; vl /= 7.f;
    float cvi = vi / (mi * mi + 1e-10f);
    float cvl = vl / (ml * ml + 1e-10f);
    out_loss[0] = 0.01f * (cvi + cvl);
  }
}

// ---------- launch ----------
extern "C" void kernel_launch(void* const* d_in, const int* in_sizes, int n_in,
                              void* d_out, int out_size, void* d_ws, size_t ws_size,
                              hipStream_t stream){
  const float* x  = (const float*)d_in[0];
  const float* nz = (const float*)d_in[1];
  const float* wg = (const float*)d_in[2];
  const float* wn = (const float*)d_in[3];
  const float* W1 = (const float*)d_in[4];
  const float* b1 = (const float*)d_in[5];
  const float* W2 = (const float*)d_in[6];
  const float* b2 = (const float*)d_in[7];
  float* y = (float*)d_out;
  float* loss = y + (size_t)8192 * 1024;

  char* ws = (char*)d_ws;
  size_t o = 0;
  auto alloc = [&](size_t bytes){ size_t r = o; o += (bytes + 255) & ~(size_t)255; return r; };
  int*  counts  = (int*)(ws + alloc(64));
  int*  cnt2    = (int*)(ws + alloc(64));
  int*  offs    = (int*)(ws + alloc(64));
  int*  btab    = (int*)(ws + alloc(1024));
  int4* rowinfo = (int4*)(ws + alloc((size_t)8192 * 16));
  int*  slot_of = (int*)(ws + alloc((size_t)16384 * 4));
  int*  tok     = (int*)(ws + alloc((size_t)16384 * 4));
  float* loadrow = (float*)(ws + alloc((size_t)8192 * 8 * 4));
  u16*  xb      = (u16*)(ws + alloc((size_t)8192 * 1024 * 2));
  u16*  w1t     = (u16*)(ws + alloc((size_t)8 * 1024 * 4096 * 2));
  u16*  w2t     = (u16*)(ws + alloc((size_t)8 * 1024 * 4096 * 2));
  u16*  h_buf   = (u16*)(ws + alloc((size_t)16384 * 4096 * 2));
  u16*  out_buf = (u16*)(ws + alloc((size_t)16384 * 1024 * 2));
  if (o > ws_size) return;

  hipMemsetAsync(ws, 0, 768, stream);  // counts, cnt2, offs

  gating_kernel<<<2048, 256, 0, stream>>>(x, nz, wg, wn, counts, rowinfo, loadrow, xb);
  transpose_cvt_kernel<<<dim3(128, 32, 8), dim3(32, 8), 0, stream>>>(W1, w1t, 1024, 4096);
  transpose_cvt_kernel<<<dim3(32, 128, 8), dim3(32, 8), 0, stream>>>(W2, w2t, 4096, 1024);
  scan_kernel<<<1, 64, 0, stream>>>(counts, offs, btab);
  fill_kernel<<<32, 256, 0, stream>>>(rowinfo, offs, cnt2, tok, slot_of);
  ffn8_kernel<1024, 4096, true,  true ><<<dim3(72, 16), 512, 0, stream>>>(xb, w1t, b1, h_buf, counts, offs, btab, tok);
  ffn8_kernel<4096, 1024, false, false><<<dim3(72, 4),  512, 0, stream>>>(h_buf, w2t, b2, out_buf, counts, offs, btab, tok);
  combine_kernel<<<8192, 256, 0, stream>>>(out_buf, rowinfo, slot_of, y);
  loss_kernel<<<1, 256, 0, stream>>>(rowinfo, loadrow, loss);
}

// Round 5
// 858.933 us; speedup vs baseline: 1.6102x; 1.0174x over previous
//
#include <hip/hip_runtime.h>

typedef unsigned short u16;
typedef unsigned int u32;
typedef __attribute__((ext_vector_type(4))) float f32x4;
typedef __attribute__((ext_vector_type(8))) short short8;
typedef __attribute__((ext_vector_type(4))) unsigned short u16x4;

#define BARR __builtin_amdgcn_s_barrier()
#define VM4  asm volatile("s_waitcnt vmcnt(4)" ::: "memory")
#define VM0  asm volatile("s_waitcnt vmcnt(0)" ::: "memory")

// ---------- helpers ----------
__device__ __forceinline__ u16 f2b(float f){
  u32 u = __float_as_uint(f);
  u = (u + 0x7FFFu + ((u >> 16) & 1u)) >> 16;   // RNE
  return (u16)u;
}
__device__ __forceinline__ float b2f(u16 h){ return __uint_as_float(((u32)h) << 16); }

__device__ __forceinline__ void gload16(const void* g, void* l){
  __builtin_amdgcn_global_load_lds((__attribute__((address_space(1))) void*)(g),
                                   (__attribute__((address_space(3))) void*)(l), 16, 0, 0);
}

// ---------- W f32 [R][C] -> bf16 transposed [C][R], per expert (vectorized) ----------
__global__ __launch_bounds__(256) void transpose_cvt_kernel(const float* __restrict__ src,
                                                            u16* __restrict__ dst,
                                                            int R, int C){
  __shared__ float t[64][65];
  int e = blockIdx.z;
  size_t eo = (size_t)R * C * e;
  int c0 = blockIdx.x * 64, r0 = blockIdx.y * 64;
  int tid = threadIdx.x;
  int lr = tid >> 4, lc4 = (tid & 15) * 4;
  #pragma unroll
  for (int i = 0; i < 4; i++){
    int r = lr + i * 16;
    float4 v = *(const float4*)&src[eo + (size_t)(r0 + r) * C + c0 + lc4];
    t[r][lc4] = v.x; t[r][lc4 + 1] = v.y; t[r][lc4 + 2] = v.z; t[r][lc4 + 3] = v.w;
  }
  __syncthreads();
  #pragma unroll
  for (int i = 0; i < 4; i++){
    int c = lr + i * 16;
    u16x4 o = { f2b(t[lc4][c]), f2b(t[lc4 + 1][c]), f2b(t[lc4 + 2][c]), f2b(t[lc4 + 3][c]) };
    *(u16x4*)&dst[eo + (size_t)(c0 + c) * R + r0 + lc4] = o;
  }
}

// ---------- gating (+ fused x->bf16), 16 rows/block ----------
__global__ __launch_bounds__(256) void gating_kernel(const float* __restrict__ x,
                                                     const float* __restrict__ nz,
                                                     const float* __restrict__ wg,
                                                     const float* __restrict__ wn,
                                                     int* __restrict__ counts,
                                                     int4* __restrict__ rowinfo,
                                                     float* __restrict__ loadrow,
                                                     u16* __restrict__ xb){
  __shared__ float wls[1024 * 16];
  int tid = threadIdx.x;
  for (int i = 0; i < 64; i++){
    int idx = i * 256 + tid;
    int d = idx >> 4, c = idx & 15;
    wls[idx] = (c < 8) ? wg[d * 8 + c] : wn[d * 8 + (c - 8)];
  }
  __syncthreads();
  int w = tid >> 6, lane = tid & 63;
  for (int rr = 0; rr < 4; rr++){
    int row = blockIdx.x * 16 + w * 4 + rr;
    float ag[8], an[8];
    #pragma unroll
    for (int e = 0; e < 8; e++){ ag[e] = 0.f; an[e] = 0.f; }
    for (int c = 0; c < 16; c++){
      int d = c * 64 + lane;
      float xv = x[(size_t)row * 1024 + d];
      xb[(size_t)row * 1024 + d] = f2b(xv);
      const float* wp = &wls[d * 16];
      #pragma unroll
      for (int e = 0; e < 8; e++){
        ag[e] = fmaf(xv, wp[e], ag[e]);
        an[e] = fmaf(xv, wp[8 + e], an[e]);
      }
    }
    #pragma unroll
    for (int off = 32; off >= 1; off >>= 1){
      #pragma unroll
      for (int e = 0; e < 8; e++){
        ag[e] += __shfl_xor(ag[e], off, 64);
        an[e] += __shfl_xor(an[e], off, 64);
      }
    }
    if (lane == 0){
      float clean[8], sd[8], noisy[8];
      #pragma unroll
      for (int e = 0; e < 8; e++){
        clean[e] = ag[e];
        float v = an[e];
        float sp = fmaxf(v, 0.f) + log1pf(expf(-fabsf(v)));
        sd[e] = sp + 0.01f;
        noisy[e] = clean[e] + nz[row * 8 + e] * sd[e];
      }
      int i0 = 0, i1 = -1;
      float b0 = -3.4e38f, b1v = -3.4e38f, b2v = -3.4e38f;
      #pragma unroll
      for (int j = 0; j < 8; j++){
        float t = noisy[j];
        if (t > b0){ b2v = b1v; b1v = b0; i1 = i0; b0 = t; i0 = j; }
        else if (t > b1v){ b2v = b1v; b1v = t; i1 = j; }
        else if (t > b2v){ b2v = t; }
      }
      float eg = expf(b1v - b0);
      float g0 = 1.f / (1.f + eg), g1 = eg / (1.f + eg);
      rowinfo[row] = make_int4(i0, i1, __float_as_int(g0), __float_as_int(g1));
      atomicAdd(&counts[i0], 1);
      atomicAdd(&counts[i1], 1);
      float thr_in = b2v, thr_out = b1v;
      #pragma unroll
      for (int e = 0; e < 8; e++){
        bool isin = noisy[e] > thr_in;
        float thr = isin ? thr_in : thr_out;
        float z = (clean[e] - thr) / sd[e];
        loadrow[row * 8 + e] = 0.5f * (1.f + erff(z * 0.70710678118654752f));
      }
    }
  }
}

// ---------- scan + block table (256-row blocks) ----------
__global__ void scan_kernel(const int* __restrict__ counts, int* __restrict__ offs,
                            int* __restrict__ btab){
  if (threadIdx.x == 0){
    int s = 0, nb = 0;
    for (int e = 0; e < 8; e++){
      offs[e] = s;
      int c = counts[e]; s += c;
      int nbe = (c + 255) >> 8;
      for (int t = 0; t < nbe; t++) btab[nb++] = (e << 16) | t;
    }
    offs[15] = nb;
  }
}

// ---------- fill dispatch lists ----------
__global__ __launch_bounds__(256) void fill_kernel(const int4* __restrict__ rowinfo,
                                                   const int* __restrict__ offs,
                                                   int* __restrict__ cnt2,
                                                   int* __restrict__ tok,
                                                   int* __restrict__ slot_of){
  int r = blockIdx.x * 256 + threadIdx.x;
  int4 ri = rowinfo[r];
  int p0 = atomicAdd(&cnt2[ri.x], 1);
  int s0 = offs[ri.x] + p0;
  tok[s0] = r; slot_of[2 * r] = s0;
  int p1 = atomicAdd(&cnt2[ri.y], 1);
  int s1 = offs[ri.y] + p1;
  tok[s1] = r; slot_of[2 * r + 1] = s1;
}

// ---------- grouped GEMM, 256x256, 8-phase, deep counted-vmcnt schedule ----------
// Stage slots (iter j: buf0=tile 2j, buf1=tile 2j+1), each region staged right
// after its last read, so every needed load has >=2 full phases in flight:
//   P1: reads b0 Q(0,0); stage A1h1<-t1   (As[1] last read P7 prev)
//   P2: reads b0 Q(0,1); stage B1h1<-t1   (Bs[1] last read P6 prev)
//   P3: reads b0 Q(1,1); stage B0h0<-t2   (Bs[0] last read P2)
//   P4: reads b0 Q(1,0) [B regs reused];  stage A0h0<-t2; vmcnt(4)
//       gate: outstanding <= {P3,P4} = t2 stages -> all of t1 landed for P5-P8.
//   P5: reads b1 Q(0,0); stage A0h1<-t2
//   P6: reads b1 Q(0,1); stage B0h1<-t2
//   P7: reads b1 Q(1,1); stage B1h0<-t3   (Bs[1] last read P6)
//   P8: reads b1 Q(1,0);  stage A1h0<-t3; vmcnt(4)
//       gate: outstanding <= {P7,P8} = t3 stages -> all of t2 landed for next P1-P4.
// Last iteration peeled: only P1/P2 stages (complete t1), vmcnt(0) at P4 (R3 lesson:
// skipped stages shift the counted ledger).
template<int KDIM, int OSTR, bool GATHER, bool RELU>
__global__ __launch_bounds__(512, 1) void ffn8_kernel(
    const u16* __restrict__ Ag, const u16* __restrict__ Bt,
    const float* __restrict__ bias, u16* __restrict__ outp,
    const int* __restrict__ counts, const int* __restrict__ offs,
    const int* __restrict__ btab, const int* __restrict__ tok)
{
  constexpr int NT = KDIM / 64;
  constexpr int NITER = NT / 2;
  __shared__ u16 As[2][2][128 * 64];
  __shared__ u16 Bs[2][2][128 * 64];

  int gx = gridDim.x;
  int lin = blockIdx.y * gx + blockIdx.x;
  int total = gx * gridDim.y, chunk = total >> 3;
  int swz = (lin & 7) * chunk + (lin >> 3);       // bijective: total % 8 == 0
  int bx = swz % gx, tn = swz / gx;
  int nblk = offs[15];
  if (bx >= nblk) return;
  int et = btab[bx]; int e = et >> 16, tm = et & 0xffff;
  int cnt = counts[e], off_e = offs[e];

  int tid = threadIdx.x, lane = tid & 63;
  int wid = tid >> 6, wm = wid >> 2, wn = wid & 3;

  // staging source byte offsets (source pre-swizzled; LDS dest linear — rule #21)
  int rl0 = tid >> 3, c8 = tid & 7;
  const char* Abase = (const char*)Ag;
  const char* Bbase = (const char*)(Bt + (size_t)e * 4194304);
  u32 aoff[4], boff[4];
  #pragma unroll
  for (int h = 0; h < 2; h++)
    #pragma unroll
    for (int r = 0; r < 2; r++){
      int rl = h * 128 + r * 64 + rl0;
      int c8s = c8 ^ (rl & 7);
      int rr = tm * 256 + rl;
      int rc = (rr < cnt) ? rr : (cnt - 1);
      size_t arow = GATHER ? (size_t)tok[off_e + rc] : (size_t)(off_e + rc);
      aoff[h * 2 + r] = (u32)(arow * (KDIM * 2) + c8s * 16);
      boff[h * 2 + r] = (u32)((size_t)(tn * 256 + rl) * (KDIM * 2) + c8s * 16);
    }
  int ldst = (tid & ~63) * 8;   // wave-uniform linear LDS dest (elements)

  auto stA = [&](int b, int h, int t){
    const char* s = Abase + (size_t)t * 128;
    gload16(s + aoff[h * 2 + 0], &As[b][h][ldst]);
    gload16(s + aoff[h * 2 + 1], &As[b][h][4096 + ldst]);
  };
  auto stB = [&](int b, int h, int t){
    const char* s = Bbase + (size_t)t * 128;
    gload16(s + boff[h * 2 + 0], &Bs[b][h][ldst]);
    gload16(s + boff[h * 2 + 1], &Bs[b][h][4096 + ldst]);
  };

  int lm = lane & 15, lkb = (lane >> 4) * 8;
  short8 Ar[4][2], Br[2][2][2];
  auto ldA = [&](int b, int rh){
    #pragma unroll
    for (int ii = 0; ii < 4; ii++){
      int rl = rh * 64 + ii * 16 + lm;
      #pragma unroll
      for (int ks = 0; ks < 2; ks++){
        int idx = (rl * 64 + ks * 32 + lkb) ^ ((rl & 7) << 3);
        Ar[ii][ks] = *(const short8*)&As[b][wm][idx];
      }
    }
  };
  auto ldB = [&](int b, int ch){
    #pragma unroll
    for (int jj = 0; jj < 2; jj++){
      int rb = wn * 64 + ch * 32 + jj * 16 + lm;
      int hB = rb >> 7, rl = rb & 127;
      #pragma unroll
      for (int ks = 0; ks < 2; ks++){
        int idx = (rl * 64 + ks * 32 + lkb) ^ ((rl & 7) << 3);
        Br[ch][jj][ks] = *(const short8*)&Bs[b][hB][idx];
      }
    }
  };

  f32x4 acc[8][4];
  #pragma unroll
  for (int i = 0; i < 8; i++)
    #pragma unroll
    for (int j = 0; j < 4; j++) acc[i][j] = (f32x4){0.f, 0.f, 0.f, 0.f};

  auto mfmaQ = [&](int rh, int ch){
    __builtin_amdgcn_s_setprio(1);
    #pragma unroll
    for (int ks = 0; ks < 2; ks++)
      #pragma unroll
      for (int ii = 0; ii < 4; ii++)
        #pragma unroll
        for (int jj = 0; jj < 2; jj++)
          acc[rh * 4 + ii][ch * 2 + jj] = __builtin_amdgcn_mfma_f32_16x16x32_bf16(
              Ar[ii][ks], Br[ch][jj][ks], acc[rh * 4 + ii][ch * 2 + jj], 0, 0, 0);
    __builtin_amdgcn_s_setprio(0);
  };

  // prologue: t0 all 4 halves -> buf0; t1's B-h0, A-h0 -> buf1
  stA(0, 0, 0); stA(0, 1, 0); stB(0, 0, 0); stB(0, 1, 0);
  stB(1, 0, 1); stA(1, 0, 1);
  VM4; BARR;

  for (int j = 0; j < NITER - 1; ++j){
    int t1 = 2 * j + 1, t2 = 2 * j + 2, t3 = 2 * j + 3;
    // P1
    ldA(0, 0); ldB(0, 0);
    stA(1, 1, t1);
    BARR; mfmaQ(0, 0); BARR;
    // P2
    ldB(0, 1);
    stB(1, 1, t1);
    BARR; mfmaQ(0, 1); BARR;
    // P3
    ldA(0, 1);
    stB(0, 0, t2);
    BARR; mfmaQ(1, 1); BARR;
    // P4 (Br[0] regs still hold buf0 ch0)
    stA(0, 0, t2);
    BARR; mfmaQ(1, 0); VM4; BARR;
    // P5
    ldA(1, 0); ldB(1, 0);
    stA(0, 1, t2);
    BARR; mfmaQ(0, 0); BARR;
    // P6
    ldB(1, 1);
    stB(0, 1, t2);
    BARR; mfmaQ(0, 1); BARR;
    // P7
    ldA(1, 1);
    stB(1, 0, t3);
    BARR; mfmaQ(1, 1); BARR;
    // P8
    stA(1, 0, t3);
    BARR; mfmaQ(1, 0); VM4; BARR;
  }

  { // peeled last iteration: only P1/P2 stage (complete tile NT-1), full drain at P4
    int t1 = NT - 1;
    ldA(0, 0); ldB(0, 0);
    stA(1, 1, t1);
    BARR; mfmaQ(0, 0); BARR;
    ldB(0, 1);
    stB(1, 1, t1);
    BARR; mfmaQ(0, 1); BARR;
    ldA(0, 1);
    BARR; mfmaQ(1, 1); BARR;
    BARR; mfmaQ(1, 0); VM0; BARR;
    ldA(1, 0); ldB(1, 0);
    BARR; mfmaQ(0, 0); BARR;
    ldB(1, 1);
    BARR; mfmaQ(0, 1); BARR;
    ldA(1, 1);
    BARR; mfmaQ(1, 1); BARR;
    BARR; mfmaQ(1, 0);
  }

  // epilogue: C write
  int lr = (lane >> 4) * 4;
  #pragma unroll
  for (int i = 0; i < 8; i++){
    int row_l = wm * 128 + i * 16 + lr;
    #pragma unroll
    for (int jj = 0; jj < 4; jj++){
      int col = tn * 256 + wn * 64 + jj * 16 + lm;
      float bv = bias[e * OSTR + col];
      #pragma unroll
      for (int q = 0; q < 4; q++){
        int r = tm * 256 + row_l + q;
        if (r < cnt){
          float v = acc[i][jj][q] + bv;
          if (RELU) v = fmaxf(v, 0.f);
          outp[(size_t)(off_e + r) * OSTR + col] = f2b(v);
        }
      }
    }
  }
}

// ---------- combine: y = g0*out[s0] + g1*out[s1] ----------
__global__ __launch_bounds__(256) void combine_kernel(const u16* __restrict__ out_buf,
                                                      const int4* __restrict__ rowinfo,
                                                      const int* __restrict__ slot_of,
                                                      float* __restrict__ y){
  int g = blockIdx.x * 256 + threadIdx.x;
  int row = g >> 8;
  int c4 = (g & 255) * 4;
  int4 ri = rowinfo[row];
  float g0 = __int_as_float(ri.z), g1 = __int_as_float(ri.w);
  int s0 = slot_of[2 * row], s1 = slot_of[2 * row + 1];
  u16x4 a = *(const u16x4*)&out_buf[((size_t)s0 << 10) + c4];
  u16x4 b = *(const u16x4*)&out_buf[((size_t)s1 << 10) + c4];
  float4 o;
  o.x = g0 * b2f(a.x) + g1 * b2f(b.x);
  o.y = g0 * b2f(a.y) + g1 * b2f(b.y);
  o.z = g0 * b2f(a.z) + g1 * b2f(b.z);
  o.w = g0 * b2f(a.w) + g1 * b2f(b.w);
  *(float4*)&y[(size_t)row * 1024 + c4] = o;
}

// ---------- loss stage 1: 32 blocks x 256 rows -> partials[32][16] ----------
__global__ __launch_bounds__(256) void loss1_kernel(const int4* __restrict__ rowinfo,
                                                    const float* __restrict__ loadrow,
                                                    float* __restrict__ partials){
  __shared__ float part[16][256];
  int tid = threadIdx.x;
  int r = blockIdx.x * 256 + tid;
  int4 ri = rowinfo[r];
  float g0 = __int_as_float(ri.z), g1 = __int_as_float(ri.w);
  f32x4 l0 = *(const f32x4*)&loadrow[r * 8];
  f32x4 l1 = *(const f32x4*)&loadrow[r * 8 + 4];
  #pragma unroll
  for (int e = 0; e < 8; e++){
    part[e][tid] = ((ri.x == e) ? g0 : 0.f) + ((ri.y == e) ? g1 : 0.f);
    part[8 + e][tid] = (e < 4) ? l0[e & 3] : l1[e & 3];
  }
  __syncthreads();
  #pragma unroll
  for (int s = 128; s >= 1; s >>= 1){
    if (tid < s){
      #pragma unroll
      for (int e = 0; e < 16; e++) part[e][tid] += part[e][tid + s];
    }
    __syncthreads();
  }
  if (tid < 16) partials[blockIdx.x * 16 + tid] = part[tid][0];
}

// ---------- loss stage 2 ----------
__global__ __launch_bounds__(64) void loss2_kernel(const float* __restrict__ partials,
                                                   float* __restrict__ out_loss){
  __shared__ float tot[16];
  int tid = threadIdx.x;
  if (tid < 16){
    float s = 0.f;
    for (int b = 0; b < 32; b++) s += partials[b * 16 + tid];
    tot[tid] = s;
  }
  __syncthreads();
  if (tid == 0){
    float mi = 0.f, ml = 0.f;
    for (int e = 0; e < 8; e++){ mi += tot[e]; ml += tot[8 + e]; }
    mi *= 0.125f; ml *= 0.125f;
    float vi = 0.f, vl = 0.f;
    for (int e = 0; e < 8; e++){
      float di = tot[e] - mi; vi += di * di;
      float dl = tot[8 + e] - ml; vl += dl * dl;
    }
    vi /= 7.f; vl /= 7.f;
    float cvi = vi / (mi * mi + 1e-10f);
    float cvl = vl / (ml * ml + 1e-10f);
    out_loss[0] = 0.01f * (cvi + cvl);
  }
}

// ---------- launch ----------
extern "C" void kernel_launch(void* const* d_in, const int* in_sizes, int n_in,
                              void* d_out, int out_size, void* d_ws, size_t ws_size,
                              hipStream_t stream){
  const float* x  = (const float*)d_in[0];
  const float* nz = (const float*)d_in[1];
  const float* wg = (const float*)d_in[2];
  const float* wn = (const float*)d_in[3];
  const float* W1 = (const float*)d_in[4];
  const float* b1 = (const float*)d_in[5];
  const float* W2 = (const float*)d_in[6];
  const float* b2 = (const float*)d_in[7];
  float* y = (float*)d_out;
  float* loss = y + (size_t)8192 * 1024;

  char* ws = (char*)d_ws;
  size_t o = 0;
  auto alloc = [&](size_t bytes){ size_t r = o; o += (bytes + 255) & ~(size_t)255; return r; };
  int*  counts  = (int*)(ws + alloc(64));
  int*  cnt2    = (int*)(ws + alloc(64));
  int*  offs    = (int*)(ws + alloc(64));
  int*  btab    = (int*)(ws + alloc(1024));
  int4* rowinfo = (int4*)(ws + alloc((size_t)8192 * 16));
  int*  slot_of = (int*)(ws + alloc((size_t)16384 * 4));
  int*  tok     = (int*)(ws + alloc((size_t)16384 * 4));
  float* loadrow = (float*)(ws + alloc((size_t)8192 * 8 * 4));
  float* partials = (float*)(ws + alloc(32 * 16 * 4));
  u16*  xb      = (u16*)(ws + alloc((size_t)8192 * 1024 * 2));
  u16*  w1t     = (u16*)(ws + alloc((size_t)8 * 1024 * 4096 * 2));
  u16*  w2t     = (u16*)(ws + alloc((size_t)8 * 1024 * 4096 * 2));
  u16*  h_buf   = (u16*)(ws + alloc((size_t)16384 * 4096 * 2));
  u16*  out_buf = (u16*)(ws + alloc((size_t)16384 * 1024 * 2));
  if (o > ws_size) return;

  hipMemsetAsync(ws, 0, 768, stream);  // counts, cnt2, offs

  gating_kernel<<<512, 256, 0, stream>>>(x, nz, wg, wn, counts, rowinfo, loadrow, xb);
  transpose_cvt_kernel<<<dim3(64, 16, 8), 256, 0, stream>>>(W1, w1t, 1024, 4096);
  transpose_cvt_kernel<<<dim3(16, 64, 8), 256, 0, stream>>>(W2, w2t, 4096, 1024);
  scan_kernel<<<1, 64, 0, stream>>>(counts, offs, btab);
  fill_kernel<<<32, 256, 0, stream>>>(rowinfo, offs, cnt2, tok, slot_of);
  ffn8_kernel<1024, 4096, true,  true ><<<dim3(72, 16), 512, 0, stream>>>(xb, w1t, b1, h_buf, counts, offs, btab, tok);
  ffn8_kernel<4096, 1024, false, false><<<dim3(72, 4),  512, 0, stream>>>(h_buf, w2t, b2, out_buf, counts, offs, btab, tok);
  combine_kernel<<<8192, 256, 0, stream>>>(out_buf, rowinfo, slot_of, y);
  loss1_kernel<<<32, 256, 0, stream>>>(rowinfo, loadrow, partials);
  loss2_kernel<<<1, 64, 0, stream>>>(partials, loss);
}

// Round 6
// 817.611 us; speedup vs baseline: 1.6916x; 1.0505x over previous
//
#include <hip/hip_runtime.h>

typedef unsigned short u16;
typedef unsigned int u32;
typedef __attribute__((ext_vector_type(4))) float f32x4;
typedef __attribute__((ext_vector_type(8))) short short8;
typedef __attribute__((ext_vector_type(4))) unsigned short u16x4;

#define BARR __builtin_amdgcn_s_barrier()
#define VM4  asm volatile("s_waitcnt vmcnt(4)" ::: "memory")
#define VM0  asm volatile("s_waitcnt vmcnt(0)" ::: "memory")

// ---------- helpers ----------
__device__ __forceinline__ u16 f2b(float f){
  u32 u = __float_as_uint(f);
  u = (u + 0x7FFFu + ((u >> 16) & 1u)) >> 16;   // RNE
  return (u16)u;
}
__device__ __forceinline__ float b2f(u16 h){ return __uint_as_float(((u32)h) << 16); }

__device__ __forceinline__ void gload16(const void* g, void* l){
  __builtin_amdgcn_global_load_lds((__attribute__((address_space(1))) void*)(g),
                                   (__attribute__((address_space(3))) void*)(l), 16, 0, 0);
}

// ---------- W f32 [R][C] -> bf16 transposed [C][R], per expert (vectorized) ----------
__global__ __launch_bounds__(256) void transpose_cvt_kernel(const float* __restrict__ src,
                                                            u16* __restrict__ dst,
                                                            int R, int C){
  __shared__ float t[64][65];
  int e = blockIdx.z;
  size_t eo = (size_t)R * C * e;
  int c0 = blockIdx.x * 64, r0 = blockIdx.y * 64;
  int tid = threadIdx.x;
  int lr = tid >> 4, lc4 = (tid & 15) * 4;
  #pragma unroll
  for (int i = 0; i < 4; i++){
    int r = lr + i * 16;
    float4 v = *(const float4*)&src[eo + (size_t)(r0 + r) * C + c0 + lc4];
    t[r][lc4] = v.x; t[r][lc4 + 1] = v.y; t[r][lc4 + 2] = v.z; t[r][lc4 + 3] = v.w;
  }
  __syncthreads();
  #pragma unroll
  for (int i = 0; i < 4; i++){
    int c = lr + i * 16;
    u16x4 o = { f2b(t[lc4][c]), f2b(t[lc4 + 1][c]), f2b(t[lc4 + 2][c]), f2b(t[lc4 + 3][c]) };
    *(u16x4*)&dst[eo + (size_t)(c0 + c) * R + r0 + lc4] = o;
  }
}

// ---------- gating (+ fused x->bf16), 16 rows/block, f32x4 LDS weight reads ----------
__global__ __launch_bounds__(256) void gating_kernel(const float* __restrict__ x,
                                                     const float* __restrict__ nz,
                                                     const float* __restrict__ wg,
                                                     const float* __restrict__ wn,
                                                     int* __restrict__ counts,
                                                     int4* __restrict__ rowinfo,
                                                     float* __restrict__ loadrow,
                                                     u16* __restrict__ xb){
  __shared__ float wls[1024 * 16];
  int tid = threadIdx.x;
  for (int i = 0; i < 64; i++){
    int idx = i * 256 + tid;
    int d = idx >> 4, c = idx & 15;
    wls[idx] = (c < 8) ? wg[d * 8 + c] : wn[d * 8 + (c - 8)];
  }
  __syncthreads();
  int w = tid >> 6, lane = tid & 63;
  for (int rr = 0; rr < 4; rr++){
    int row = blockIdx.x * 16 + w * 4 + rr;
    float ag[8], an[8];
    #pragma unroll
    for (int e = 0; e < 8; e++){ ag[e] = 0.f; an[e] = 0.f; }
    for (int c = 0; c < 16; c++){
      int d = c * 64 + lane;
      float xv = x[(size_t)row * 1024 + d];
      xb[(size_t)row * 1024 + d] = f2b(xv);
      const float4* wp = (const float4*)&wls[d * 16];
      float4 w0 = wp[0], w1 = wp[1], w2 = wp[2], w3 = wp[3];
      ag[0] = fmaf(xv, w0.x, ag[0]); ag[1] = fmaf(xv, w0.y, ag[1]);
      ag[2] = fmaf(xv, w0.z, ag[2]); ag[3] = fmaf(xv, w0.w, ag[3]);
      ag[4] = fmaf(xv, w1.x, ag[4]); ag[5] = fmaf(xv, w1.y, ag[5]);
      ag[6] = fmaf(xv, w1.z, ag[6]); ag[7] = fmaf(xv, w1.w, ag[7]);
      an[0] = fmaf(xv, w2.x, an[0]); an[1] = fmaf(xv, w2.y, an[1]);
      an[2] = fmaf(xv, w2.z, an[2]); an[3] = fmaf(xv, w2.w, an[3]);
      an[4] = fmaf(xv, w3.x, an[4]); an[5] = fmaf(xv, w3.y, an[5]);
      an[6] = fmaf(xv, w3.z, an[6]); an[7] = fmaf(xv, w3.w, an[7]);
    }
    #pragma unroll
    for (int off = 32; off >= 1; off >>= 1){
      #pragma unroll
      for (int e = 0; e < 8; e++){
        ag[e] += __shfl_xor(ag[e], off, 64);
        an[e] += __shfl_xor(an[e], off, 64);
      }
    }
    if (lane == 0){
      float clean[8], sd[8], noisy[8];
      #pragma unroll
      for (int e = 0; e < 8; e++){
        clean[e] = ag[e];
        float v = an[e];
        float sp = fmaxf(v, 0.f) + log1pf(expf(-fabsf(v)));
        sd[e] = sp + 0.01f;
        noisy[e] = clean[e] + nz[row * 8 + e] * sd[e];
      }
      int i0 = 0, i1 = -1;
      float b0 = -3.4e38f, b1v = -3.4e38f, b2v = -3.4e38f;
      #pragma unroll
      for (int j = 0; j < 8; j++){
        float t = noisy[j];
        if (t > b0){ b2v = b1v; b1v = b0; i1 = i0; b0 = t; i0 = j; }
        else if (t > b1v){ b2v = b1v; b1v = t; i1 = j; }
        else if (t > b2v){ b2v = t; }
      }
      float eg = expf(b1v - b0);
      float g0 = 1.f / (1.f + eg), g1 = eg / (1.f + eg);
      rowinfo[row] = make_int4(i0, i1, __float_as_int(g0), __float_as_int(g1));
      atomicAdd(&counts[i0], 1);
      atomicAdd(&counts[i1], 1);
      float thr_in = b2v, thr_out = b1v;
      #pragma unroll
      for (int e = 0; e < 8; e++){
        bool isin = noisy[e] > thr_in;
        float thr = isin ? thr_in : thr_out;
        float z = (clean[e] - thr) / sd[e];
        loadrow[row * 8 + e] = 0.5f * (1.f + erff(z * 0.70710678118654752f));
      }
    }
  }
}

// ---------- scan + block table (256-row blocks) ----------
__global__ void scan_kernel(const int* __restrict__ counts, int* __restrict__ offs,
                            int* __restrict__ btab){
  if (threadIdx.x == 0){
    int s = 0, nb = 0;
    for (int e = 0; e < 8; e++){
      offs[e] = s;
      int c = counts[e]; s += c;
      int nbe = (c + 255) >> 8;
      for (int t = 0; t < nbe; t++) btab[nb++] = (e << 16) | t;
    }
    offs[15] = nb;
  }
}

// ---------- fill dispatch lists ----------
__global__ __launch_bounds__(256) void fill_kernel(const int4* __restrict__ rowinfo,
                                                   const int* __restrict__ offs,
                                                   int* __restrict__ cnt2,
                                                   int* __restrict__ tok,
                                                   int* __restrict__ slot_of){
  int r = blockIdx.x * 256 + threadIdx.x;
  int4 ri = rowinfo[r];
  int p0 = atomicAdd(&cnt2[ri.x], 1);
  int s0 = offs[ri.x] + p0;
  tok[s0] = r; slot_of[2 * r] = s0;
  int p1 = atomicAdd(&cnt2[ri.y], 1);
  int s1 = offs[ri.y] + p1;
  tok[s1] = r; slot_of[2 * r + 1] = s1;
}

// ---------- grouped GEMM, 256x256, 8-phase counted-vmcnt + early-read overlap ----------
// Main-loop phase map (iter j: buf0=tile 2j, buf1=tile 2j+1); reads for P2/P3/P6/P7
// are issued at the END of the previous phase (post-MFMA) — their source buffer was
// validated >=1 vmcnt-gate earlier and is disjoint from all concurrently-staged
// regions (WAR audited per phase). P1/P5 reads stay at phase start (they need the
// immediately-preceding gate's collective validation). Last iteration peeled with
// vmcnt(0) (R3 lesson: skipped stages shift the counted ledger).
// K-split support: kbase shifts A/B base pointers; niter is runtime; F32OUT writes
// raw f32 partials (no bias/relu) selected by kh into p0/p1.
template<int KDIM, bool GATHER, bool RELU, bool F32OUT>
__global__ __launch_bounds__(512, 1) void ffn8_kernel(
    const u16* __restrict__ Ag, const u16* __restrict__ Bt,
    const float* __restrict__ bias, u16* __restrict__ outp,
    float* __restrict__ pp0, float* __restrict__ pp1,
    const int* __restrict__ counts, const int* __restrict__ offs,
    const int* __restrict__ btab, const int* __restrict__ tok,
    int nc, int klen, int ostr)
{
  __shared__ u16 As[2][2][128 * 64];
  __shared__ u16 Bs[2][2][128 * 64];

  int gx = gridDim.x;
  int lin = blockIdx.y * gx + blockIdx.x;
  int total = gx * gridDim.y, chunk = total >> 3;
  int swz = (lin & 7) * chunk + (lin >> 3);       // bijective: total % 8 == 0
  int bx = swz % gx, tq = swz / gx;
  int nblk = offs[15];
  if (bx >= nblk) return;
  int kh = (tq >= nc) ? 1 : 0;
  int tn = tq - kh * nc;
  int kbase = kh * klen;
  int niter = klen >> 7;                          // klen/128 (2 tiles/iter)
  int et = btab[bx]; int e = et >> 16, tm = et & 0xffff;
  int cnt = counts[e], off_e = offs[e];

  int tid = threadIdx.x, lane = tid & 63;
  int wid = tid >> 6, wm = wid >> 2, wn = wid & 3;

  // staging source byte offsets (source pre-swizzled; LDS dest linear — rule #21)
  int rl0 = tid >> 3, c8 = tid & 7;
  const char* Abase = (const char*)Ag + (size_t)kbase * 2;
  const char* Bbase = (const char*)(Bt + (size_t)e * 4194304) + (size_t)kbase * 2;
  u32 aoff[4], boff[4];
  #pragma unroll
  for (int h = 0; h < 2; h++)
    #pragma unroll
    for (int r = 0; r < 2; r++){
      int rl = h * 128 + r * 64 + rl0;
      int c8s = c8 ^ (rl & 7);
      int rr = tm * 256 + rl;
      int rc = (rr < cnt) ? rr : (cnt - 1);
      size_t arow = GATHER ? (size_t)tok[off_e + rc] : (size_t)(off_e + rc);
      aoff[h * 2 + r] = (u32)(arow * (KDIM * 2) + c8s * 16);
      boff[h * 2 + r] = (u32)((size_t)(tn * 256 + rl) * (KDIM * 2) + c8s * 16);
    }
  int ldst = (tid & ~63) * 8;   // wave-uniform linear LDS dest (elements)

  auto stA = [&](int b, int h, int t){
    const char* s = Abase + (size_t)t * 128;
    gload16(s + aoff[h * 2 + 0], &As[b][h][ldst]);
    gload16(s + aoff[h * 2 + 1], &As[b][h][4096 + ldst]);
  };
  auto stB = [&](int b, int h, int t){
    const char* s = Bbase + (size_t)t * 128;
    gload16(s + boff[h * 2 + 0], &Bs[b][h][ldst]);
    gload16(s + boff[h * 2 + 1], &Bs[b][h][4096 + ldst]);
  };

  int lm = lane & 15, lkb = (lane >> 4) * 8;
  short8 Ar[4][2], Br[2][2][2];
  auto ldA = [&](int b, int rh){
    #pragma unroll
    for (int ii = 0; ii < 4; ii++){
      int rl = rh * 64 + ii * 16 + lm;
      #pragma unroll
      for (int ks = 0; ks < 2; ks++){
        int idx = (rl * 64 + ks * 32 + lkb) ^ ((rl & 7) << 3);
        Ar[ii][ks] = *(const short8*)&As[b][wm][idx];
      }
    }
  };
  auto ldB = [&](int b, int ch){
    #pragma unroll
    for (int jj = 0; jj < 2; jj++){
      int rb = wn * 64 + ch * 32 + jj * 16 + lm;
      int hB = rb >> 7, rl = rb & 127;
      #pragma unroll
      for (int ks = 0; ks < 2; ks++){
        int idx = (rl * 64 + ks * 32 + lkb) ^ ((rl & 7) << 3);
        Br[ch][jj][ks] = *(const short8*)&Bs[b][hB][idx];
      }
    }
  };

  f32x4 acc[8][4];
  #pragma unroll
  for (int i = 0; i < 8; i++)
    #pragma unroll
    for (int j = 0; j < 4; j++) acc[i][j] = (f32x4){0.f, 0.f, 0.f, 0.f};

  auto mfmaQ = [&](int rh, int ch){
    __builtin_amdgcn_s_setprio(1);
    #pragma unroll
    for (int ks = 0; ks < 2; ks++)
      #pragma unroll
      for (int ii = 0; ii < 4; ii++)
        #pragma unroll
        for (int jj = 0; jj < 2; jj++)
          acc[rh * 4 + ii][ch * 2 + jj] = __builtin_amdgcn_mfma_f32_16x16x32_bf16(
              Ar[ii][ks], Br[ch][jj][ks], acc[rh * 4 + ii][ch * 2 + jj], 0, 0, 0);
    __builtin_amdgcn_s_setprio(0);
  };

  // prologue: t0 all 4 halves -> buf0; t1's B-h0, A-h0 -> buf1
  stA(0, 0, 0); stA(0, 1, 0); stB(0, 0, 0); stB(0, 1, 0);
  stB(1, 0, 1); stA(1, 0, 1);
  VM4; BARR;

  for (int j = 0; j < niter - 1; ++j){
    int t1 = 2 * j + 1, t2 = 2 * j + 2, t3 = 2 * j + 3;
    // P1
    ldA(0, 0); ldB(0, 0);
    stA(1, 1, t1);
    BARR; mfmaQ(0, 0); ldB(0, 1); BARR;
    // P2
    stB(1, 1, t1);
    BARR; mfmaQ(0, 1); ldA(0, 1); BARR;
    // P3
    stB(0, 0, t2);
    BARR; mfmaQ(1, 1); BARR;
    // P4 (Br[0] regs still hold buf0 ch0)
    stA(0, 0, t2);
    BARR; mfmaQ(1, 0); VM4; BARR;
    // P5
    ldA(1, 0); ldB(1, 0);
    stA(0, 1, t2);
    BARR; mfmaQ(0, 0); ldB(1, 1); BARR;
    // P6
    stB(0, 1, t2);
    BARR; mfmaQ(0, 1); ldA(1, 1); BARR;
    // P7
    stB(1, 0, t3);
    BARR; mfmaQ(1, 1); BARR;
    // P8
    stA(1, 0, t3);
    BARR; mfmaQ(1, 0); VM4; BARR;
  }

  { // peeled last iteration: only P1/P2 stage (complete tile NT-1), full drain at P4
    int t1 = (klen >> 6) - 1;
    ldA(0, 0); ldB(0, 0);
    stA(1, 1, t1);
    BARR; mfmaQ(0, 0); ldB(0, 1); BARR;
    stB(1, 1, t1);
    BARR; mfmaQ(0, 1); ldA(0, 1); BARR;
    BARR; mfmaQ(1, 1); BARR;
    mfmaQ(1, 0); VM0; BARR;
    ldA(1, 0); ldB(1, 0);
    BARR; mfmaQ(0, 0); ldB(1, 1); BARR;
    BARR; mfmaQ(0, 1); ldA(1, 1); BARR;
    BARR; mfmaQ(1, 1); BARR;
    mfmaQ(1, 0);
  }

  // epilogue: C write
  int lr = (lane >> 4) * 4;
  float* pout = kh ? pp1 : pp0;
  #pragma unroll
  for (int i = 0; i < 8; i++){
    int row_l = wm * 128 + i * 16 + lr;
    #pragma unroll
    for (int jj = 0; jj < 4; jj++){
      int col = tn * 256 + wn * 64 + jj * 16 + lm;
      float bv = F32OUT ? 0.f : bias[e * ostr + col];
      #pragma unroll
      for (int q = 0; q < 4; q++){
        int r = tm * 256 + row_l + q;
        if (r < cnt){
          float v = acc[i][jj][q] + bv;
          if (RELU) v = fmaxf(v, 0.f);
          if (F32OUT) pout[(size_t)(off_e + r) * ostr + col] = v;
          else        outp[(size_t)(off_e + r) * ostr + col] = f2b(v);
        }
      }
    }
  }
}

// ---------- combine: y = g0*(p0[s0]+p1[s0]+b2[e0]) + g1*(p0[s1]+p1[s1]+b2[e1]) ----------
__global__ __launch_bounds__(256) void combine_kernel(const float* __restrict__ p0,
                                                      const float* __restrict__ p1,
                                                      const float* __restrict__ b2,
                                                      const int4* __restrict__ rowinfo,
                                                      const int* __restrict__ slot_of,
                                                      float* __restrict__ y){
  int g = blockIdx.x * 256 + threadIdx.x;
  int row = g >> 8;
  int c4 = (g & 255) * 4;
  int4 ri = rowinfo[row];
  float g0 = __int_as_float(ri.z), g1 = __int_as_float(ri.w);
  int s0 = slot_of[2 * row], s1 = slot_of[2 * row + 1];
  float4 a0 = *(const float4*)&p0[((size_t)s0 << 10) + c4];
  float4 a1 = *(const float4*)&p1[((size_t)s0 << 10) + c4];
  float4 b0 = *(const float4*)&p0[((size_t)s1 << 10) + c4];
  float4 b1 = *(const float4*)&p1[((size_t)s1 << 10) + c4];
  float4 e0 = *(const float4*)&b2[(ri.x << 10) + c4];
  float4 e1 = *(const float4*)&b2[(ri.y << 10) + c4];
  float4 o;
  o.x = g0 * (a0.x + a1.x + e0.x) + g1 * (b0.x + b1.x + e1.x);
  o.y = g0 * (a0.y + a1.y + e0.y) + g1 * (b0.y + b1.y + e1.y);
  o.z = g0 * (a0.z + a1.z + e0.z) + g1 * (b0.z + b1.z + e1.z);
  o.w = g0 * (a0.w + a1.w + e0.w) + g1 * (b0.w + b1.w + e1.w);
  *(float4*)&y[(size_t)row * 1024 + c4] = o;
}

// ---------- loss stage 1: 32 blocks x 256 rows -> partials[32][16] ----------
__global__ __launch_bounds__(256) void loss1_kernel(const int4* __restrict__ rowinfo,
                                                    const float* __restrict__ loadrow,
                                                    float* __restrict__ partials){
  __shared__ float part[16][256];
  int tid = threadIdx.x;
  int r = blockIdx.x * 256 + tid;
  int4 ri = rowinfo[r];
  float g0 = __int_as_float(ri.z), g1 = __int_as_float(ri.w);
  f32x4 l0 = *(const f32x4*)&loadrow[r * 8];
  f32x4 l1 = *(const f32x4*)&loadrow[r * 8 + 4];
  #pragma unroll
  for (int e = 0; e < 8; e++){
    part[e][tid] = ((ri.x == e) ? g0 : 0.f) + ((ri.y == e) ? g1 : 0.f);
    part[8 + e][tid] = (e < 4) ? l0[e & 3] : l1[e & 3];
  }
  __syncthreads();
  #pragma unroll
  for (int s = 128; s >= 1; s >>= 1){
    if (tid < s){
      #pragma unroll
      for (int e = 0; e < 16; e++) part[e][tid] += part[e][tid + s];
    }
    __syncthreads();
  }
  if (tid < 16) partials[blockIdx.x * 16 + tid] = part[tid][0];
}

// ---------- loss stage 2 ----------
__global__ __launch_bounds__(64) void loss2_kernel(const float* __restrict__ partials,
                                                   float* __restrict__ out_loss){
  __shared__ float tot[16];
  int tid = threadIdx.x;
  if (tid < 16){
    float s = 0.f;
    for (int b = 0; b < 32; b++) s += partials[b * 16 + tid];
    tot[tid] = s;
  }
  __syncthreads();
  if (tid == 0){
    float mi = 0.f, ml = 0.f;
    for (int e = 0; e < 8; e++){ mi += tot[e]; ml += tot[8 + e]; }
    mi *= 0.125f; ml *= 0.125f;
    float vi = 0.f, vl = 0.f;
    for (int e = 0; e < 8; e++){
      float di = tot[e] - mi; vi += di * di;
      float dl = tot[8 + e] - ml; vl += dl * dl;
    }
    vi /= 7.f; vl /= 7.f;
    float cvi = vi / (mi * mi + 1e-10f);
    float cvl = vl / (ml * ml + 1e-10f);
    out_loss[0] = 0.01f * (cvi + cvl);
  }
}

// ---------- launch ----------
extern "C" void kernel_launch(void* const* d_in, const int* in_sizes, int n_in,
                              void* d_out, int out_size, void* d_ws, size_t ws_size,
                              hipStream_t stream){
  const float* x  = (const float*)d_in[0];
  const float* nz = (const float*)d_in[1];
  const float* wg = (const float*)d_in[2];
  const float* wn = (const float*)d_in[3];
  const float* W1 = (const float*)d_in[4];
  const float* b1 = (const float*)d_in[5];
  const float* W2 = (const float*)d_in[6];
  const float* b2 = (const float*)d_in[7];
  float* y = (float*)d_out;
  float* loss = y + (size_t)8192 * 1024;

  char* ws = (char*)d_ws;
  size_t o = 0;
  auto alloc = [&](size_t bytes){ size_t r = o; o += (bytes + 255) & ~(size_t)255; return r; };
  int*  counts  = (int*)(ws + alloc(64));
  int*  cnt2    = (int*)(ws + alloc(64));
  int*  offs    = (int*)(ws + alloc(64));
  int*  btab    = (int*)(ws + alloc(1024));
  int4* rowinfo = (int4*)(ws + alloc((size_t)8192 * 16));
  int*  slot_of = (int*)(ws + alloc((size_t)16384 * 4));
  int*  tok     = (int*)(ws + alloc((size_t)16384 * 4));
  float* loadrow = (float*)(ws + alloc((size_t)8192 * 8 * 4));
  float* partials = (float*)(ws + alloc(32 * 16 * 4));
  u16*  xb      = (u16*)(ws + alloc((size_t)8192 * 1024 * 2));
  u16*  w1t     = (u16*)(ws + alloc((size_t)8 * 1024 * 4096 * 2));
  u16*  w2t     = (u16*)(ws + alloc((size_t)8 * 1024 * 4096 * 2));
  u16*  h_buf   = (u16*)(ws + alloc((size_t)16384 * 4096 * 2));
  float* p0     = (float*)(ws + alloc((size_t)16384 * 1024 * 4));
  float* p1     = (float*)(ws + alloc((size_t)16384 * 1024 * 4));
  if (o > ws_size) return;

  hipMemsetAsync(ws, 0, 768, stream);  // counts, cnt2, offs

  gating_kernel<<<512, 256, 0, stream>>>(x, nz, wg, wn, counts, rowinfo, loadrow, xb);
  transpose_cvt_kernel<<<dim3(64, 16, 8), 256, 0, stream>>>(W1, w1t, 1024, 4096);
  transpose_cvt_kernel<<<dim3(16, 64, 8), 256, 0, stream>>>(W2, w2t, 4096, 1024);
  scan_kernel<<<1, 64, 0, stream>>>(counts, offs, btab);
  fill_kernel<<<32, 256, 0, stream>>>(rowinfo, offs, cnt2, tok, slot_of);
  // ffn1: full K=1024, bf16 out with bias+relu
  ffn8_kernel<1024, true, true, false><<<dim3(72, 16), 512, 0, stream>>>(
      xb, w1t, b1, h_buf, nullptr, nullptr, counts, offs, btab, tok, 16, 1024, 4096);
  // ffn2: K split 2x2048 in ONE dispatch (kh from grid), f32 partials, no bias/relu
  ffn8_kernel<4096, false, false, true><<<dim3(72, 8), 512, 0, stream>>>(
      h_buf, w2t, nullptr, nullptr, p0, p1, counts, offs, btab, tok, 4, 2048, 1024);
  combine_kernel<<<8192, 256, 0, stream>>>(p0, p1, b2, rowinfo, slot_of, y);
  loss1_kernel<<<32, 256, 0, stream>>>(rowinfo, loadrow, partials);
  loss2_kernel<<<1, 64, 0, stream>>>(partials, loss);
}

// Round 7
// 698.701 us; speedup vs baseline: 1.9795x; 1.1702x over previous
//
#include <hip/hip_runtime.h>

typedef unsigned short u16;
typedef unsigned int u32;
typedef __attribute__((ext_vector_type(4))) float f32x4;
typedef __attribute__((ext_vector_type(8))) short short8;
typedef __attribute__((ext_vector_type(4))) unsigned short u16x4;

#define BARR __builtin_amdgcn_s_barrier()
#define VM4  asm volatile("s_waitcnt vmcnt(4)" ::: "memory")
#define VM0  asm volatile("s_waitcnt vmcnt(0)" ::: "memory")

// ---------- helpers ----------
__device__ __forceinline__ u16 f2b(float f){
  u32 u = __float_as_uint(f);
  u = (u + 0x7FFFu + ((u >> 16) & 1u)) >> 16;   // RNE
  return (u16)u;
}
__device__ __forceinline__ float b2f(u16 h){ return __uint_as_float(((u32)h) << 16); }

__device__ __forceinline__ void gload16(const void* g, void* l){
  __builtin_amdgcn_global_load_lds((__attribute__((address_space(1))) void*)(g),
                                   (__attribute__((address_space(3))) void*)(l), 16, 0, 0);
}

// ---------- W f32 [R][C] -> bf16 transposed [C][R], per expert (vectorized) ----------
__global__ __launch_bounds__(256) void transpose_cvt_kernel(const float* __restrict__ src,
                                                            u16* __restrict__ dst,
                                                            int R, int C){
  __shared__ float t[64][65];
  int e = blockIdx.z;
  size_t eo = (size_t)R * C * e;
  int c0 = blockIdx.x * 64, r0 = blockIdx.y * 64;
  int tid = threadIdx.x;
  int lr = tid >> 4, lc4 = (tid & 15) * 4;
  #pragma unroll
  for (int i = 0; i < 4; i++){
    int r = lr + i * 16;
    float4 v = *(const float4*)&src[eo + (size_t)(r0 + r) * C + c0 + lc4];
    t[r][lc4] = v.x; t[r][lc4 + 1] = v.y; t[r][lc4 + 2] = v.z; t[r][lc4 + 3] = v.w;
  }
  __syncthreads();
  #pragma unroll
  for (int i = 0; i < 4; i++){
    int c = lr + i * 16;
    u16x4 o = { f2b(t[lc4][c]), f2b(t[lc4 + 1][c]), f2b(t[lc4 + 2][c]), f2b(t[lc4 + 3][c]) };
    *(u16x4*)&dst[eo + (size_t)(c0 + c) * R + r0 + lc4] = o;
  }
}

// ---------- gating v2: register weights, float4 x loads, batched epilogue ----------
// Wave w owns d in [w*256,(w+1)*256); lane owns d0 = w*256+lane*4 .. +3.
// Weights (64 KB total) loaded once per block into 64 regs/lane (L2-hot gather).
// Per row: float4 x load + fused bf16 conversion + 64 FMA + 6-stage shfl_xor
// reduce of 16 values; lane0 stores wave-partial to padded LDS (no per-row barrier).
// One barrier, then 16 lanes each finish one row (4-way sum + softplus + top-3 +
// Phi + atomics) fully lane-parallel.
__global__ __launch_bounds__(256) void gating_kernel(const float* __restrict__ x,
                                                     const float* __restrict__ nz,
                                                     const float* __restrict__ wg,
                                                     const float* __restrict__ wn,
                                                     int* __restrict__ counts,
                                                     int4* __restrict__ rowinfo,
                                                     float* __restrict__ loadrow,
                                                     u16* __restrict__ xb){
  __shared__ float wpart[16][4][17];   // [row][wave][val], pad 17 to break conflicts
  int tid = threadIdx.x, w = tid >> 6, lane = tid & 63;
  int d0 = w * 256 + lane * 4;
  float4 wgA[4], wgB[4], wnA[4], wnB[4];
  #pragma unroll
  for (int k = 0; k < 4; k++){
    wgA[k] = *(const float4*)&wg[(d0 + k) * 8];
    wgB[k] = *(const float4*)&wg[(d0 + k) * 8 + 4];
    wnA[k] = *(const float4*)&wn[(d0 + k) * 8];
    wnB[k] = *(const float4*)&wn[(d0 + k) * 8 + 4];
  }
  int rbase = blockIdx.x * 16;
  for (int r = 0; r < 16; r++){
    int row = rbase + r;
    float4 xv = *(const float4*)&x[(size_t)row * 1024 + d0];
    u16x4 xo = { f2b(xv.x), f2b(xv.y), f2b(xv.z), f2b(xv.w) };
    *(u16x4*)&xb[(size_t)row * 1024 + d0] = xo;
    float ag[8], an[8];
    #pragma unroll
    for (int e = 0; e < 8; e++){ ag[e] = 0.f; an[e] = 0.f; }
    float xk[4] = { xv.x, xv.y, xv.z, xv.w };
    #pragma unroll
    for (int k = 0; k < 4; k++){
      ag[0] = fmaf(xk[k], wgA[k].x, ag[0]); ag[1] = fmaf(xk[k], wgA[k].y, ag[1]);
      ag[2] = fmaf(xk[k], wgA[k].z, ag[2]); ag[3] = fmaf(xk[k], wgA[k].w, ag[3]);
      ag[4] = fmaf(xk[k], wgB[k].x, ag[4]); ag[5] = fmaf(xk[k], wgB[k].y, ag[5]);
      ag[6] = fmaf(xk[k], wgB[k].z, ag[6]); ag[7] = fmaf(xk[k], wgB[k].w, ag[7]);
      an[0] = fmaf(xk[k], wnA[k].x, an[0]); an[1] = fmaf(xk[k], wnA[k].y, an[1]);
      an[2] = fmaf(xk[k], wnA[k].z, an[2]); an[3] = fmaf(xk[k], wnA[k].w, an[3]);
      an[4] = fmaf(xk[k], wnB[k].x, an[4]); an[5] = fmaf(xk[k], wnB[k].y, an[5]);
      an[6] = fmaf(xk[k], wnB[k].z, an[6]); an[7] = fmaf(xk[k], wnB[k].w, an[7]);
    }
    #pragma unroll
    for (int off = 32; off >= 1; off >>= 1){
      #pragma unroll
      for (int e = 0; e < 8; e++){
        ag[e] += __shfl_xor(ag[e], off, 64);
        an[e] += __shfl_xor(an[e], off, 64);
      }
    }
    if (lane == 0){
      #pragma unroll
      for (int e = 0; e < 8; e++){
        wpart[r][w][e] = ag[e];
        wpart[r][w][8 + e] = an[e];
      }
    }
  }
  __syncthreads();
  if (tid < 16){
    int r = tid, row = rbase + r;
    float cg[16];
    #pragma unroll
    for (int v = 0; v < 16; v++)
      cg[v] = wpart[r][0][v] + wpart[r][1][v] + wpart[r][2][v] + wpart[r][3][v];
    float clean[8], sd[8], noisy[8];
    #pragma unroll
    for (int e = 0; e < 8; e++){
      clean[e] = cg[e];
      float v = cg[8 + e];
      float sp = fmaxf(v, 0.f) + log1pf(expf(-fabsf(v)));
      sd[e] = sp + 0.01f;
      noisy[e] = clean[e] + nz[row * 8 + e] * sd[e];
    }
    int i0 = 0, i1 = -1;
    float b0 = -3.4e38f, b1v = -3.4e38f, b2v = -3.4e38f;
    #pragma unroll
    for (int j = 0; j < 8; j++){
      float t = noisy[j];
      if (t > b0){ b2v = b1v; b1v = b0; i1 = i0; b0 = t; i0 = j; }
      else if (t > b1v){ b2v = b1v; b1v = t; i1 = j; }
      else if (t > b2v){ b2v = t; }
    }
    float eg = expf(b1v - b0);
    float g0 = 1.f / (1.f + eg), g1 = eg / (1.f + eg);
    rowinfo[row] = make_int4(i0, i1, __float_as_int(g0), __float_as_int(g1));
    atomicAdd(&counts[i0], 1);
    atomicAdd(&counts[i1], 1);
    float thr_in = b2v, thr_out = b1v;
    #pragma unroll
    for (int e = 0; e < 8; e++){
      bool isin = noisy[e] > thr_in;
      float thr = isin ? thr_in : thr_out;
      float z = (clean[e] - thr) / sd[e];
      loadrow[row * 8 + e] = 0.5f * (1.f + erff(z * 0.70710678118654752f));
    }
  }
}

// ---------- scan + block table (256-row blocks) ----------
__global__ void scan_kernel(const int* __restrict__ counts, int* __restrict__ offs,
                            int* __restrict__ btab){
  if (threadIdx.x == 0){
    int s = 0, nb = 0;
    for (int e = 0; e < 8; e++){
      offs[e] = s;
      int c = counts[e]; s += c;
      int nbe = (c + 255) >> 8;
      for (int t = 0; t < nbe; t++) btab[nb++] = (e << 16) | t;
    }
    offs[15] = nb;
  }
}

// ---------- fill dispatch lists ----------
__global__ __launch_bounds__(256) void fill_kernel(const int4* __restrict__ rowinfo,
                                                   const int* __restrict__ offs,
                                                   int* __restrict__ cnt2,
                                                   int* __restrict__ tok,
                                                   int* __restrict__ slot_of){
  int r = blockIdx.x * 256 + threadIdx.x;
  int4 ri = rowinfo[r];
  int p0 = atomicAdd(&cnt2[ri.x], 1);
  int s0 = offs[ri.x] + p0;
  tok[s0] = r; slot_of[2 * r] = s0;
  int p1 = atomicAdd(&cnt2[ri.y], 1);
  int s1 = offs[ri.y] + p1;
  tok[s1] = r; slot_of[2 * r + 1] = s1;
}

// ---------- grouped GEMM, 256x256, 8-phase counted-vmcnt + early-read overlap ----------
// (unchanged from R6 — see R6 comments for the phase map and vmcnt ledger)
template<int KDIM, bool GATHER, bool RELU, bool F32OUT>
__global__ __launch_bounds__(512, 1) void ffn8_kernel(
    const u16* __restrict__ Ag, const u16* __restrict__ Bt,
    const float* __restrict__ bias, u16* __restrict__ outp,
    float* __restrict__ pp0, float* __restrict__ pp1,
    const int* __restrict__ counts, const int* __restrict__ offs,
    const int* __restrict__ btab, const int* __restrict__ tok,
    int nc, int klen, int ostr)
{
  __shared__ u16 As[2][2][128 * 64];
  __shared__ u16 Bs[2][2][128 * 64];

  int gx = gridDim.x;
  int lin = blockIdx.y * gx + blockIdx.x;
  int total = gx * gridDim.y, chunk = total >> 3;
  int swz = (lin & 7) * chunk + (lin >> 3);       // bijective: total % 8 == 0
  int bx = swz % gx, tq = swz / gx;
  int nblk = offs[15];
  if (bx >= nblk) return;
  int kh = (tq >= nc) ? 1 : 0;
  int tn = tq - kh * nc;
  int kbase = kh * klen;
  int niter = klen >> 7;                          // klen/128 (2 tiles/iter)
  int et = btab[bx]; int e = et >> 16, tm = et & 0xffff;
  int cnt = counts[e], off_e = offs[e];

  int tid = threadIdx.x, lane = tid & 63;
  int wid = tid >> 6, wm = wid >> 2, wn = wid & 3;

  // staging source byte offsets (source pre-swizzled; LDS dest linear — rule #21)
  int rl0 = tid >> 3, c8 = tid & 7;
  const char* Abase = (const char*)Ag + (size_t)kbase * 2;
  const char* Bbase = (const char*)(Bt + (size_t)e * 4194304) + (size_t)kbase * 2;
  u32 aoff[4], boff[4];
  #pragma unroll
  for (int h = 0; h < 2; h++)
    #pragma unroll
    for (int r = 0; r < 2; r++){
      int rl = h * 128 + r * 64 + rl0;
      int c8s = c8 ^ (rl & 7);
      int rr = tm * 256 + rl;
      int rc = (rr < cnt) ? rr : (cnt - 1);
      size_t arow = GATHER ? (size_t)tok[off_e + rc] : (size_t)(off_e + rc);
      aoff[h * 2 + r] = (u32)(arow * (KDIM * 2) + c8s * 16);
      boff[h * 2 + r] = (u32)((size_t)(tn * 256 + rl) * (KDIM * 2) + c8s * 16);
    }
  int ldst = (tid & ~63) * 8;   // wave-uniform linear LDS dest (elements)

  auto stA = [&](int b, int h, int t){
    const char* s = Abase + (size_t)t * 128;
    gload16(s + aoff[h * 2 + 0], &As[b][h][ldst]);
    gload16(s + aoff[h * 2 + 1], &As[b][h][4096 + ldst]);
  };
  auto stB = [&](int b, int h, int t){
    const char* s = Bbase + (size_t)t * 128;
    gload16(s + boff[h * 2 + 0], &Bs[b][h][ldst]);
    gload16(s + boff[h * 2 + 1], &Bs[b][h][4096 + ldst]);
  };

  int lm = lane & 15, lkb = (lane >> 4) * 8;
  short8 Ar[4][2], Br[2][2][2];
  auto ldA = [&](int b, int rh){
    #pragma unroll
    for (int ii = 0; ii < 4; ii++){
      int rl = rh * 64 + ii * 16 + lm;
      #pragma unroll
      for (int ks = 0; ks < 2; ks++){
        int idx = (rl * 64 + ks * 32 + lkb) ^ ((rl & 7) << 3);
        Ar[ii][ks] = *(const short8*)&As[b][wm][idx];
      }
    }
  };
  auto ldB = [&](int b, int ch){
    #pragma unroll
    for (int jj = 0; jj < 2; jj++){
      int rb = wn * 64 + ch * 32 + jj * 16 + lm;
      int hB = rb >> 7, rl = rb & 127;
      #pragma unroll
      for (int ks = 0; ks < 2; ks++){
        int idx = (rl * 64 + ks * 32 + lkb) ^ ((rl & 7) << 3);
        Br[ch][jj][ks] = *(const short8*)&Bs[b][hB][idx];
      }
    }
  };

  f32x4 acc[8][4];
  #pragma unroll
  for (int i = 0; i < 8; i++)
    #pragma unroll
    for (int j = 0; j < 4; j++) acc[i][j] = (f32x4){0.f, 0.f, 0.f, 0.f};

  auto mfmaQ = [&](int rh, int ch){
    __builtin_amdgcn_s_setprio(1);
    #pragma unroll
    for (int ks = 0; ks < 2; ks++)
      #pragma unroll
      for (int ii = 0; ii < 4; ii++)
        #pragma unroll
        for (int jj = 0; jj < 2; jj++)
          acc[rh * 4 + ii][ch * 2 + jj] = __builtin_amdgcn_mfma_f32_16x16x32_bf16(
              Ar[ii][ks], Br[ch][jj][ks], acc[rh * 4 + ii][ch * 2 + jj], 0, 0, 0);
    __builtin_amdgcn_s_setprio(0);
  };

  // prologue: t0 all 4 halves -> buf0; t1's B-h0, A-h0 -> buf1
  stA(0, 0, 0); stA(0, 1, 0); stB(0, 0, 0); stB(0, 1, 0);
  stB(1, 0, 1); stA(1, 0, 1);
  VM4; BARR;

  for (int j = 0; j < niter - 1; ++j){
    int t1 = 2 * j + 1, t2 = 2 * j + 2, t3 = 2 * j + 3;
    // P1
    ldA(0, 0); ldB(0, 0);
    stA(1, 1, t1);
    BARR; mfmaQ(0, 0); ldB(0, 1); BARR;
    // P2
    stB(1, 1, t1);
    BARR; mfmaQ(0, 1); ldA(0, 1); BARR;
    // P3
    stB(0, 0, t2);
    BARR; mfmaQ(1, 1); BARR;
    // P4 (Br[0] regs still hold buf0 ch0)
    stA(0, 0, t2);
    BARR; mfmaQ(1, 0); VM4; BARR;
    // P5
    ldA(1, 0); ldB(1, 0);
    stA(0, 1, t2);
    BARR; mfmaQ(0, 0); ldB(1, 1); BARR;
    // P6
    stB(0, 1, t2);
    BARR; mfmaQ(0, 1); ldA(1, 1); BARR;
    // P7
    stB(1, 0, t3);
    BARR; mfmaQ(1, 1); BARR;
    // P8
    stA(1, 0, t3);
    BARR; mfmaQ(1, 0); VM4; BARR;
  }

  { // peeled last iteration: only P1/P2 stage (complete tile NT-1), full drain at P4
    int t1 = (klen >> 6) - 1;
    ldA(0, 0); ldB(0, 0);
    stA(1, 1, t1);
    BARR; mfmaQ(0, 0); ldB(0, 1); BARR;
    stB(1, 1, t1);
    BARR; mfmaQ(0, 1); ldA(0, 1); BARR;
    BARR; mfmaQ(1, 1); BARR;
    mfmaQ(1, 0); VM0; BARR;
    ldA(1, 0); ldB(1, 0);
    BARR; mfmaQ(0, 0); ldB(1, 1); BARR;
    BARR; mfmaQ(0, 1); ldA(1, 1); BARR;
    BARR; mfmaQ(1, 1); BARR;
    mfmaQ(1, 0);
  }

  // epilogue: C write
  int lr = (lane >> 4) * 4;
  float* pout = kh ? pp1 : pp0;
  #pragma unroll
  for (int i = 0; i < 8; i++){
    int row_l = wm * 128 + i * 16 + lr;
    #pragma unroll
    for (int jj = 0; jj < 4; jj++){
      int col = tn * 256 + wn * 64 + jj * 16 + lm;
      float bv = F32OUT ? 0.f : bias[e * ostr + col];
      #pragma unroll
      for (int q = 0; q < 4; q++){
        int r = tm * 256 + row_l + q;
        if (r < cnt){
          float v = acc[i][jj][q] + bv;
          if (RELU) v = fmaxf(v, 0.f);
          if (F32OUT) pout[(size_t)(off_e + r) * ostr + col] = v;
          else        outp[(size_t)(off_e + r) * ostr + col] = f2b(v);
        }
      }
    }
  }
}

// ---------- combine: y = g0*(p0[s0]+p1[s0]+b2[e0]) + g1*(p0[s1]+p1[s1]+b2[e1]) ----------
__global__ __launch_bounds__(256) void combine_kernel(const float* __restrict__ p0,
                                                      const float* __restrict__ p1,
                                                      const float* __restrict__ b2,
                                                      const int4* __restrict__ rowinfo,
                                                      const int* __restrict__ slot_of,
                                                      float* __restrict__ y){
  int g = blockIdx.x * 256 + threadIdx.x;
  int row = g >> 8;
  int c4 = (g & 255) * 4;
  int4 ri = rowinfo[row];
  float g0 = __int_as_float(ri.z), g1 = __int_as_float(ri.w);
  int s0 = slot_of[2 * row], s1 = slot_of[2 * row + 1];
  float4 a0 = *(const float4*)&p0[((size_t)s0 << 10) + c4];
  float4 a1 = *(const float4*)&p1[((size_t)s0 << 10) + c4];
  float4 b0 = *(const float4*)&p0[((size_t)s1 << 10) + c4];
  float4 b1 = *(const float4*)&p1[((size_t)s1 << 10) + c4];
  float4 e0 = *(const float4*)&b2[(ri.x << 10) + c4];
  float4 e1 = *(const float4*)&b2[(ri.y << 10) + c4];
  float4 o;
  o.x = g0 * (a0.x + a1.x + e0.x) + g1 * (b0.x + b1.x + e1.x);
  o.y = g0 * (a0.y + a1.y + e0.y) + g1 * (b0.y + b1.y + e1.y);
  o.z = g0 * (a0.z + a1.z + e0.z) + g1 * (b0.z + b1.z + e1.z);
  o.w = g0 * (a0.w + a1.w + e0.w) + g1 * (b0.w + b1.w + e1.w);
  *(float4*)&y[(size_t)row * 1024 + c4] = o;
}

// ---------- loss stage 1: 32 blocks x 256 rows -> partials[32][16] ----------
__global__ __launch_bounds__(256) void loss1_kernel(const int4* __restrict__ rowinfo,
                                                    const float* __restrict__ loadrow,
                                                    float* __restrict__ partials){
  __shared__ float part[16][256];
  int tid = threadIdx.x;
  int r = blockIdx.x * 256 + tid;
  int4 ri = rowinfo[r];
  float g0 = __int_as_float(ri.z), g1 = __int_as_float(ri.w);
  f32x4 l0 = *(const f32x4*)&loadrow[r * 8];
  f32x4 l1 = *(const f32x4*)&loadrow[r * 8 + 4];
  #pragma unroll
  for (int e = 0; e < 8; e++){
    part[e][tid] = ((ri.x == e) ? g0 : 0.f) + ((ri.y == e) ? g1 : 0.f);
    part[8 + e][tid] = (e < 4) ? l0[e & 3] : l1[e & 3];
  }
  __syncthreads();
  #pragma unroll
  for (int s = 128; s >= 1; s >>= 1){
    if (tid < s){
      #pragma unroll
      for (int e = 0; e < 16; e++) part[e][tid] += part[e][tid + s];
    }
    __syncthreads();
  }
  if (tid < 16) partials[blockIdx.x * 16 + tid] = part[tid][0];
}

// ---------- loss stage 2 ----------
__global__ __launch_bounds__(64) void loss2_kernel(const float* __restrict__ partials,
                                                   float* __restrict__ out_loss){
  __shared__ float tot[16];
  int tid = threadIdx.x;
  if (tid < 16){
    float s = 0.f;
    for (int b = 0; b < 32; b++) s += partials[b * 16 + tid];
    tot[tid] = s;
  }
  __syncthreads();
  if (tid == 0){
    float mi = 0.f, ml = 0.f;
    for (int e = 0; e < 8; e++){ mi += tot[e]; ml += tot[8 + e]; }
    mi *= 0.125f; ml *= 0.125f;
    float vi = 0.f, vl = 0.f;
    for (int e = 0; e < 8; e++){
      float di = tot[e] - mi; vi += di * di;
      float dl = tot[8 + e] - ml; vl += dl * dl;
    }
    vi /= 7.f; vl /= 7.f;
    float cvi = vi / (mi * mi + 1e-10f);
    float cvl = vl / (ml * ml + 1e-10f);
    out_loss[0] = 0.01f * (cvi + cvl);
  }
}

// ---------- launch ----------
extern "C" void kernel_launch(void* const* d_in, const int* in_sizes, int n_in,
                              void* d_out, int out_size, void* d_ws, size_t ws_size,
                              hipStream_t stream){
  const float* x  = (const float*)d_in[0];
  const float* nz = (const float*)d_in[1];
  const float* wg = (const float*)d_in[2];
  const float* wn = (const float*)d_in[3];
  const float* W1 = (const float*)d_in[4];
  const float* b1 = (const float*)d_in[5];
  const float* W2 = (const float*)d_in[6];
  const float* b2 = (const float*)d_in[7];
  float* y = (float*)d_out;
  float* loss = y + (size_t)8192 * 1024;

  char* ws = (char*)d_ws;
  size_t o = 0;
  auto alloc = [&](size_t bytes){ size_t r = o; o += (bytes + 255) & ~(size_t)255; return r; };
  int*  counts  = (int*)(ws + alloc(64));
  int*  cnt2    = (int*)(ws + alloc(64));
  int*  offs    = (int*)(ws + alloc(64));
  int*  btab    = (int*)(ws + alloc(1024));
  int4* rowinfo = (int4*)(ws + alloc((size_t)8192 * 16));
  int*  slot_of = (int*)(ws + alloc((size_t)16384 * 4));
  int*  tok     = (int*)(ws + alloc((size_t)16384 * 4));
  float* loadrow = (float*)(ws + alloc((size_t)8192 * 8 * 4));
  float* partials = (float*)(ws + alloc(32 * 16 * 4));
  u16*  xb      = (u16*)(ws + alloc((size_t)8192 * 1024 * 2));
  u16*  w1t     = (u16*)(ws + alloc((size_t)8 * 1024 * 4096 * 2));
  u16*  w2t     = (u16*)(ws + alloc((size_t)8 * 1024 * 4096 * 2));
  u16*  h_buf   = (u16*)(ws + alloc((size_t)16384 * 4096 * 2));
  float* p0     = (float*)(ws + alloc((size_t)16384 * 1024 * 4));
  float* p1     = (float*)(ws + alloc((size_t)16384 * 1024 * 4));
  if (o > ws_size) return;

  hipMemsetAsync(ws, 0, 768, stream);  // counts, cnt2, offs

  gating_kernel<<<512, 256, 0, stream>>>(x, nz, wg, wn, counts, rowinfo, loadrow, xb);
  transpose_cvt_kernel<<<dim3(64, 16, 8), 256, 0, stream>>>(W1, w1t, 1024, 4096);
  transpose_cvt_kernel<<<dim3(16, 64, 8), 256, 0, stream>>>(W2, w2t, 4096, 1024);
  scan_kernel<<<1, 64, 0, stream>>>(counts, offs, btab);
  fill_kernel<<<32, 256, 0, stream>>>(rowinfo, offs, cnt2, tok, slot_of);
  // ffn1: full K=1024, bf16 out with bias+relu
  ffn8_kernel<1024, true, true, false><<<dim3(72, 16), 512, 0, stream>>>(
      xb, w1t, b1, h_buf, nullptr, nullptr, counts, offs, btab, tok, 16, 1024, 4096);
  // ffn2: K split 2x2048 in ONE dispatch (kh from grid), f32 partials, no bias/relu
  ffn8_kernel<4096, false, false, true><<<dim3(72, 8), 512, 0, stream>>>(
      h_buf, w2t, nullptr, nullptr, p0, p1, counts, offs, btab, tok, 4, 2048, 1024);
  combine_kernel<<<8192, 256, 0, stream>>>(p0, p1, b2, rowinfo, slot_of, y);
  loss1_kernel<<<32, 256, 0, stream>>>(rowinfo, loadrow, partials);
  loss2_kernel<<<1, 64, 0, stream>>>(partials, loss);
}

// Round 8
// 685.435 us; speedup vs baseline: 2.0178x; 1.0194x over previous
//
#include <hip/hip_runtime.h>

typedef unsigned short u16;
typedef unsigned int u32;
typedef __attribute__((ext_vector_type(4))) float f32x4;
typedef __attribute__((ext_vector_type(8))) short short8;
typedef __attribute__((ext_vector_type(4))) unsigned short u16x4;

#define BARR __builtin_amdgcn_s_barrier()
#define VM4  asm volatile("s_waitcnt vmcnt(4)" ::: "memory")
#define VM0  asm volatile("s_waitcnt vmcnt(0)" ::: "memory")

// ---------- helpers ----------
__device__ __forceinline__ u16 f2b(float f){
  u32 u = __float_as_uint(f);
  u = (u + 0x7FFFu + ((u >> 16) & 1u)) >> 16;   // RNE
  return (u16)u;
}
__device__ __forceinline__ float b2f(u16 h){ return __uint_as_float(((u32)h) << 16); }

__device__ __forceinline__ void gload16(const void* g, void* l){
  __builtin_amdgcn_global_load_lds((__attribute__((address_space(1))) void*)(g),
                                   (__attribute__((address_space(3))) void*)(l), 16, 0, 0);
}

// ---------- W f32 [R][C] -> bf16 transposed [C][R], per expert (vectorized) ----------
__global__ __launch_bounds__(256) void transpose_cvt_kernel(const float* __restrict__ src,
                                                            u16* __restrict__ dst,
                                                            int R, int C){
  __shared__ float t[64][65];
  int e = blockIdx.z;
  size_t eo = (size_t)R * C * e;
  int c0 = blockIdx.x * 64, r0 = blockIdx.y * 64;
  int tid = threadIdx.x;
  int lr = tid >> 4, lc4 = (tid & 15) * 4;
  #pragma unroll
  for (int i = 0; i < 4; i++){
    int r = lr + i * 16;
    float4 v = *(const float4*)&src[eo + (size_t)(r0 + r) * C + c0 + lc4];
    t[r][lc4] = v.x; t[r][lc4 + 1] = v.y; t[r][lc4 + 2] = v.z; t[r][lc4 + 3] = v.w;
  }
  __syncthreads();
  #pragma unroll
  for (int i = 0; i < 4; i++){
    int c = lr + i * 16;
    u16x4 o = { f2b(t[lc4][c]), f2b(t[lc4 + 1][c]), f2b(t[lc4 + 2][c]), f2b(t[lc4 + 3][c]) };
    *(u16x4*)&dst[eo + (size_t)(c0 + c) * R + r0 + lc4] = o;
  }
}

// ---------- gating v2 (R7, proven): register weights, batched epilogue ----------
__global__ __launch_bounds__(256) void gating_kernel(const float* __restrict__ x,
                                                     const float* __restrict__ nz,
                                                     const float* __restrict__ wg,
                                                     const float* __restrict__ wn,
                                                     int* __restrict__ counts,
                                                     int4* __restrict__ rowinfo,
                                                     float* __restrict__ loadrow,
                                                     u16* __restrict__ xb){
  __shared__ float wpart[16][4][17];
  int tid = threadIdx.x, w = tid >> 6, lane = tid & 63;
  int d0 = w * 256 + lane * 4;
  float4 wgA[4], wgB[4], wnA[4], wnB[4];
  #pragma unroll
  for (int k = 0; k < 4; k++){
    wgA[k] = *(const float4*)&wg[(d0 + k) * 8];
    wgB[k] = *(const float4*)&wg[(d0 + k) * 8 + 4];
    wnA[k] = *(const float4*)&wn[(d0 + k) * 8];
    wnB[k] = *(const float4*)&wn[(d0 + k) * 8 + 4];
  }
  int rbase = blockIdx.x * 16;
  for (int r = 0; r < 16; r++){
    int row = rbase + r;
    float4 xv = *(const float4*)&x[(size_t)row * 1024 + d0];
    u16x4 xo = { f2b(xv.x), f2b(xv.y), f2b(xv.z), f2b(xv.w) };
    *(u16x4*)&xb[(size_t)row * 1024 + d0] = xo;
    float ag[8], an[8];
    #pragma unroll
    for (int e = 0; e < 8; e++){ ag[e] = 0.f; an[e] = 0.f; }
    float xk[4] = { xv.x, xv.y, xv.z, xv.w };
    #pragma unroll
    for (int k = 0; k < 4; k++){
      ag[0] = fmaf(xk[k], wgA[k].x, ag[0]); ag[1] = fmaf(xk[k], wgA[k].y, ag[1]);
      ag[2] = fmaf(xk[k], wgA[k].z, ag[2]); ag[3] = fmaf(xk[k], wgA[k].w, ag[3]);
      ag[4] = fmaf(xk[k], wgB[k].x, ag[4]); ag[5] = fmaf(xk[k], wgB[k].y, ag[5]);
      ag[6] = fmaf(xk[k], wgB[k].z, ag[6]); ag[7] = fmaf(xk[k], wgB[k].w, ag[7]);
      an[0] = fmaf(xk[k], wnA[k].x, an[0]); an[1] = fmaf(xk[k], wnA[k].y, an[1]);
      an[2] = fmaf(xk[k], wnA[k].z, an[2]); an[3] = fmaf(xk[k], wnA[k].w, an[3]);
      an[4] = fmaf(xk[k], wnB[k].x, an[4]); an[5] = fmaf(xk[k], wnB[k].y, an[5]);
      an[6] = fmaf(xk[k], wnB[k].z, an[6]); an[7] = fmaf(xk[k], wnB[k].w, an[7]);
    }
    #pragma unroll
    for (int off = 32; off >= 1; off >>= 1){
      #pragma unroll
      for (int e = 0; e < 8; e++){
        ag[e] += __shfl_xor(ag[e], off, 64);
        an[e] += __shfl_xor(an[e], off, 64);
      }
    }
    if (lane == 0){
      #pragma unroll
      for (int e = 0; e < 8; e++){
        wpart[r][w][e] = ag[e];
        wpart[r][w][8 + e] = an[e];
      }
    }
  }
  __syncthreads();
  if (tid < 16){
    int r = tid, row = rbase + r;
    float cg[16];
    #pragma unroll
    for (int v = 0; v < 16; v++)
      cg[v] = wpart[r][0][v] + wpart[r][1][v] + wpart[r][2][v] + wpart[r][3][v];
    float clean[8], sd[8], noisy[8];
    #pragma unroll
    for (int e = 0; e < 8; e++){
      clean[e] = cg[e];
      float v = cg[8 + e];
      float sp = fmaxf(v, 0.f) + log1pf(expf(-fabsf(v)));
      sd[e] = sp + 0.01f;
      noisy[e] = clean[e] + nz[row * 8 + e] * sd[e];
    }
    int i0 = 0, i1 = -1;
    float b0 = -3.4e38f, b1v = -3.4e38f, b2v = -3.4e38f;
    #pragma unroll
    for (int j = 0; j < 8; j++){
      float t = noisy[j];
      if (t > b0){ b2v = b1v; b1v = b0; i1 = i0; b0 = t; i0 = j; }
      else if (t > b1v){ b2v = b1v; b1v = t; i1 = j; }
      else if (t > b2v){ b2v = t; }
    }
    float eg = expf(b1v - b0);
    float g0 = 1.f / (1.f + eg), g1 = eg / (1.f + eg);
    rowinfo[row] = make_int4(i0, i1, __float_as_int(g0), __float_as_int(g1));
    atomicAdd(&counts[i0], 1);
    atomicAdd(&counts[i1], 1);
    float thr_in = b2v, thr_out = b1v;
    #pragma unroll
    for (int e = 0; e < 8; e++){
      bool isin = noisy[e] > thr_in;
      float thr = isin ? thr_in : thr_out;
      float z = (clean[e] - thr) / sd[e];
      loadrow[row * 8 + e] = 0.5f * (1.f + erff(z * 0.70710678118654752f));
    }
  }
}

// ---------- scan + block table (256-row blocks) ----------
__global__ void scan_kernel(const int* __restrict__ counts, int* __restrict__ offs,
                            int* __restrict__ btab){
  if (threadIdx.x == 0){
    int s = 0, nb = 0;
    for (int e = 0; e < 8; e++){
      offs[e] = s;
      int c = counts[e]; s += c;
      int nbe = (c + 255) >> 8;
      for (int t = 0; t < nbe; t++) btab[nb++] = (e << 16) | t;
    }
    offs[15] = nb;
  }
}

// ---------- fill dispatch lists ----------
__global__ __launch_bounds__(256) void fill_kernel(const int4* __restrict__ rowinfo,
                                                   const int* __restrict__ offs,
                                                   int* __restrict__ cnt2,
                                                   int* __restrict__ tok,
                                                   int* __restrict__ slot_of){
  int r = blockIdx.x * 256 + threadIdx.x;
  int4 ri = rowinfo[r];
  int p0 = atomicAdd(&cnt2[ri.x], 1);
  int s0 = offs[ri.x] + p0;
  tok[s0] = r; slot_of[2 * r] = s0;
  int p1 = atomicAdd(&cnt2[ri.y], 1);
  int s1 = offs[ri.y] + p1;
  tok[s1] = r; slot_of[2 * r + 1] = s1;
}

// ---------- grouped GEMM, 256x256, 8-phase counted-vmcnt + early-read overlap ----------
// Schedule identical to R6/R7 (ledger-audited, peeled last iter). New: generalized
// (kh, tn) decode — tq = kh*nc + tn — so ffn2 K-splits 4x1024 into bf16 partials
// (PSPLIT: out += kh*pstride, no bias/relu). Every tile in both dispatches is now
// K=1024 (8 iters): uniform cost, finer tail quantization.
template<int KDIM, bool GATHER, bool RELU, bool PSPLIT>
__global__ __launch_bounds__(512, 1) void ffn8_kernel(
    const u16* __restrict__ Ag, const u16* __restrict__ Bt,
    const float* __restrict__ bias, u16* __restrict__ outp,
    const int* __restrict__ counts, const int* __restrict__ offs,
    const int* __restrict__ btab, const int* __restrict__ tok,
    int nc, int klen, int ostr, size_t pstride)
{
  __shared__ u16 As[2][2][128 * 64];
  __shared__ u16 Bs[2][2][128 * 64];

  int gx = gridDim.x;
  int lin = blockIdx.y * gx + blockIdx.x;
  int total = gx * gridDim.y, chunk = total >> 3;
  int swz = (lin & 7) * chunk + (lin >> 3);       // bijective: total % 8 == 0
  int bx = swz % gx, tq = swz / gx;
  int nblk = offs[15];
  if (bx >= nblk) return;
  int kh = tq / nc;
  int tn = tq - kh * nc;
  int kbase = kh * klen;
  int niter = klen >> 7;                          // klen/128 (2 tiles/iter)
  int et = btab[bx]; int e = et >> 16, tm = et & 0xffff;
  int cnt = counts[e], off_e = offs[e];

  int tid = threadIdx.x, lane = tid & 63;
  int wid = tid >> 6, wm = wid >> 2, wn = wid & 3;

  // staging source byte offsets (source pre-swizzled; LDS dest linear — rule #21)
  int rl0 = tid >> 3, c8 = tid & 7;
  const char* Abase = (const char*)Ag + (size_t)kbase * 2;
  const char* Bbase = (const char*)(Bt + (size_t)e * 4194304) + (size_t)kbase * 2;
  u32 aoff[4], boff[4];
  #pragma unroll
  for (int h = 0; h < 2; h++)
    #pragma unroll
    for (int r = 0; r < 2; r++){
      int rl = h * 128 + r * 64 + rl0;
      int c8s = c8 ^ (rl & 7);
      int rr = tm * 256 + rl;
      int rc = (rr < cnt) ? rr : (cnt - 1);
      size_t arow = GATHER ? (size_t)tok[off_e + rc] : (size_t)(off_e + rc);
      aoff[h * 2 + r] = (u32)(arow * (KDIM * 2) + c8s * 16);
      boff[h * 2 + r] = (u32)((size_t)(tn * 256 + rl) * (KDIM * 2) + c8s * 16);
    }
  int ldst = (tid & ~63) * 8;   // wave-uniform linear LDS dest (elements)

  auto stA = [&](int b, int h, int t){
    const char* s = Abase + (size_t)t * 128;
    gload16(s + aoff[h * 2 + 0], &As[b][h][ldst]);
    gload16(s + aoff[h * 2 + 1], &As[b][h][4096 + ldst]);
  };
  auto stB = [&](int b, int h, int t){
    const char* s = Bbase + (size_t)t * 128;
    gload16(s + boff[h * 2 + 0], &Bs[b][h][ldst]);
    gload16(s + boff[h * 2 + 1], &Bs[b][h][4096 + ldst]);
  };

  int lm = lane & 15, lkb = (lane >> 4) * 8;
  short8 Ar[4][2], Br[2][2][2];
  auto ldA = [&](int b, int rh){
    #pragma unroll
    for (int ii = 0; ii < 4; ii++){
      int rl = rh * 64 + ii * 16 + lm;
      #pragma unroll
      for (int ks = 0; ks < 2; ks++){
        int idx = (rl * 64 + ks * 32 + lkb) ^ ((rl & 7) << 3);
        Ar[ii][ks] = *(const short8*)&As[b][wm][idx];
      }
    }
  };
  auto ldB = [&](int b, int ch){
    #pragma unroll
    for (int jj = 0; jj < 2; jj++){
      int rb = wn * 64 + ch * 32 + jj * 16 + lm;
      int hB = rb >> 7, rl = rb & 127;
      #pragma unroll
      for (int ks = 0; ks < 2; ks++){
        int idx = (rl * 64 + ks * 32 + lkb) ^ ((rl & 7) << 3);
        Br[ch][jj][ks] = *(const short8*)&Bs[b][hB][idx];
      }
    }
  };

  f32x4 acc[8][4];
  #pragma unroll
  for (int i = 0; i < 8; i++)
    #pragma unroll
    for (int j = 0; j < 4; j++) acc[i][j] = (f32x4){0.f, 0.f, 0.f, 0.f};

  auto mfmaQ = [&](int rh, int ch){
    __builtin_amdgcn_s_setprio(1);
    #pragma unroll
    for (int ks = 0; ks < 2; ks++)
      #pragma unroll
      for (int ii = 0; ii < 4; ii++)
        #pragma unroll
        for (int jj = 0; jj < 2; jj++)
          acc[rh * 4 + ii][ch * 2 + jj] = __builtin_amdgcn_mfma_f32_16x16x32_bf16(
              Ar[ii][ks], Br[ch][jj][ks], acc[rh * 4 + ii][ch * 2 + jj], 0, 0, 0);
    __builtin_amdgcn_s_setprio(0);
  };

  // prologue: t0 all 4 halves -> buf0; t1's B-h0, A-h0 -> buf1
  stA(0, 0, 0); stA(0, 1, 0); stB(0, 0, 0); stB(0, 1, 0);
  stB(1, 0, 1); stA(1, 0, 1);
  VM4; BARR;

  for (int j = 0; j < niter - 1; ++j){
    int t1 = 2 * j + 1, t2 = 2 * j + 2, t3 = 2 * j + 3;
    // P1
    ldA(0, 0); ldB(0, 0);
    stA(1, 1, t1);
    BARR; mfmaQ(0, 0); ldB(0, 1); BARR;
    // P2
    stB(1, 1, t1);
    BARR; mfmaQ(0, 1); ldA(0, 1); BARR;
    // P3
    stB(0, 0, t2);
    BARR; mfmaQ(1, 1); BARR;
    // P4 (Br[0] regs still hold buf0 ch0)
    stA(0, 0, t2);
    BARR; mfmaQ(1, 0); VM4; BARR;
    // P5
    ldA(1, 0); ldB(1, 0);
    stA(0, 1, t2);
    BARR; mfmaQ(0, 0); ldB(1, 1); BARR;
    // P6
    stB(0, 1, t2);
    BARR; mfmaQ(0, 1); ldA(1, 1); BARR;
    // P7
    stB(1, 0, t3);
    BARR; mfmaQ(1, 1); BARR;
    // P8
    stA(1, 0, t3);
    BARR; mfmaQ(1, 0); VM4; BARR;
  }

  { // peeled last iteration: only P1/P2 stage (complete tile NT-1), full drain at P4
    int t1 = (klen >> 6) - 1;
    ldA(0, 0); ldB(0, 0);
    stA(1, 1, t1);
    BARR; mfmaQ(0, 0); ldB(0, 1); BARR;
    stB(1, 1, t1);
    BARR; mfmaQ(0, 1); ldA(0, 1); BARR;
    BARR; mfmaQ(1, 1); BARR;
    mfmaQ(1, 0); VM0; BARR;
    ldA(1, 0); ldB(1, 0);
    BARR; mfmaQ(0, 0); ldB(1, 1); BARR;
    BARR; mfmaQ(0, 1); ldA(1, 1); BARR;
    BARR; mfmaQ(1, 1); BARR;
    mfmaQ(1, 0);
  }

  // epilogue: C write (PSPLIT: raw bf16 partial into kh-th buffer, no bias/relu)
  int lr = (lane >> 4) * 4;
  u16* po = outp + (PSPLIT ? (size_t)kh * pstride : 0);
  #pragma unroll
  for (int i = 0; i < 8; i++){
    int row_l = wm * 128 + i * 16 + lr;
    #pragma unroll
    for (int jj = 0; jj < 4; jj++){
      int col = tn * 256 + wn * 64 + jj * 16 + lm;
      float bv = PSPLIT ? 0.f : bias[e * ostr + col];
      #pragma unroll
      for (int q = 0; q < 4; q++){
        int r = tm * 256 + row_l + q;
        if (r < cnt){
          float v = acc[i][jj][q] + bv;
          if (RELU) v = fmaxf(v, 0.f);
          po[(size_t)(off_e + r) * ostr + col] = f2b(v);
        }
      }
    }
  }
}

// ---------- combine: y = g0*(sum_kh p[kh][s0] + b2[e0]) + g1*(...) ----------
__global__ __launch_bounds__(256) void combine_kernel(const u16* __restrict__ pb,
                                                      const float* __restrict__ b2,
                                                      const int4* __restrict__ rowinfo,
                                                      const int* __restrict__ slot_of,
                                                      float* __restrict__ y){
  const size_t PS = (size_t)16384 * 1024;
  int g = blockIdx.x * 256 + threadIdx.x;
  int row = g >> 8;
  int c4 = (g & 255) * 4;
  int4 ri = rowinfo[row];
  float g0 = __int_as_float(ri.z), g1 = __int_as_float(ri.w);
  int s0 = slot_of[2 * row], s1 = slot_of[2 * row + 1];
  float4 sum0 = *(const float4*)&b2[(ri.x << 10) + c4];
  float4 sum1 = *(const float4*)&b2[(ri.y << 10) + c4];
  #pragma unroll
  for (int kh = 0; kh < 4; kh++){
    u16x4 a = *(const u16x4*)&pb[kh * PS + ((size_t)s0 << 10) + c4];
    u16x4 b = *(const u16x4*)&pb[kh * PS + ((size_t)s1 << 10) + c4];
    sum0.x += b2f(a.x); sum0.y += b2f(a.y); sum0.z += b2f(a.z); sum0.w += b2f(a.w);
    sum1.x += b2f(b.x); sum1.y += b2f(b.y); sum1.z += b2f(b.z); sum1.w += b2f(b.w);
  }
  float4 o;
  o.x = g0 * sum0.x + g1 * sum1.x;
  o.y = g0 * sum0.y + g1 * sum1.y;
  o.z = g0 * sum0.z + g1 * sum1.z;
  o.w = g0 * sum0.w + g1 * sum1.w;
  *(float4*)&y[(size_t)row * 1024 + c4] = o;
}

// ---------- loss stage 1: 32 blocks x 256 rows -> partials[32][16] ----------
__global__ __launch_bounds__(256) void loss1_kernel(const int4* __restrict__ rowinfo,
                                                    const float* __restrict__ loadrow,
                                                    float* __restrict__ partials){
  __shared__ float part[16][256];
  int tid = threadIdx.x;
  int r = blockIdx.x * 256 + tid;
  int4 ri = rowinfo[r];
  float g0 = __int_as_float(ri.z), g1 = __int_as_float(ri.w);
  f32x4 l0 = *(const f32x4*)&loadrow[r * 8];
  f32x4 l1 = *(const f32x4*)&loadrow[r * 8 + 4];
  #pragma unroll
  for (int e = 0; e < 8; e++){
    part[e][tid] = ((ri.x == e) ? g0 : 0.f) + ((ri.y == e) ? g1 : 0.f);
    part[8 + e][tid] = (e < 4) ? l0[e & 3] : l1[e & 3];
  }
  __syncthreads();
  #pragma unroll
  for (int s = 128; s >= 1; s >>= 1){
    if (tid < s){
      #pragma unroll
      for (int e = 0; e < 16; e++) part[e][tid] += part[e][tid + s];
    }
    __syncthreads();
  }
  if (tid < 16) partials[blockIdx.x * 16 + tid] = part[tid][0];
}

// ---------- loss stage 2 ----------
__global__ __launch_bounds__(64) void loss2_kernel(const float* __restrict__ partials,
                                                   float* __restrict__ out_loss){
  __shared__ float tot[16];
  int tid = threadIdx.x;
  if (tid < 16){
    float s = 0.f;
    for (int b = 0; b < 32; b++) s += partials[b * 16 + tid];
    tot[tid] = s;
  }
  __syncthreads();
  if (tid == 0){
    float mi = 0.f, ml = 0.f;
    for (int e = 0; e < 8; e++){ mi += tot[e]; ml += tot[8 + e]; }
    mi *= 0.125f; ml *= 0.125f;
    float vi = 0.f, vl = 0.f;
    for (int e = 0; e < 8; e++){
      float di = tot[e] - mi; vi += di * di;
      float dl = tot[8 + e] - ml; vl += dl * dl;
    }
    vi /= 7.f; vl /= 7.f;
    float cvi = vi / (mi * mi + 1e-10f);
    float cvl = vl / (ml * ml + 1e-10f);
    out_loss[0] = 0.01f * (cvi + cvl);
  }
}

// ---------- launch ----------
extern "C" void kernel_launch(void* const* d_in, const int* in_sizes, int n_in,
                              void* d_out, int out_size, void* d_ws, size_t ws_size,
                              hipStream_t stream){
  const float* x  = (const float*)d_in[0];
  const float* nz = (const float*)d_in[1];
  const float* wg = (const float*)d_in[2];
  const float* wn = (const float*)d_in[3];
  const float* W1 = (const float*)d_in[4];
  const float* b1 = (const float*)d_in[5];
  const float* W2 = (const float*)d_in[6];
  const float* b2 = (const float*)d_in[7];
  float* y = (float*)d_out;
  float* loss = y + (size_t)8192 * 1024;

  char* ws = (char*)d_ws;
  size_t o = 0;
  auto alloc = [&](size_t bytes){ size_t r = o; o += (bytes + 255) & ~(size_t)255; return r; };
  int*  counts  = (int*)(ws + alloc(64));
  int*  cnt2    = (int*)(ws + alloc(64));
  int*  offs    = (int*)(ws + alloc(64));
  int*  btab    = (int*)(ws + alloc(1024));
  int4* rowinfo = (int4*)(ws + alloc((size_t)8192 * 16));
  int*  slot_of = (int*)(ws + alloc((size_t)16384 * 4));
  int*  tok     = (int*)(ws + alloc((size_t)16384 * 4));
  float* loadrow = (float*)(ws + alloc((size_t)8192 * 8 * 4));
  float* partials = (float*)(ws + alloc(32 * 16 * 4));
  u16*  xb      = (u16*)(ws + alloc((size_t)8192 * 1024 * 2));
  u16*  w1t     = (u16*)(ws + alloc((size_t)8 * 1024 * 4096 * 2));
  u16*  w2t     = (u16*)(ws + alloc((size_t)8 * 1024 * 4096 * 2));
  u16*  h_buf   = (u16*)(ws + alloc((size_t)16384 * 4096 * 2));
  u16*  pbuf    = (u16*)(ws + alloc((size_t)4 * 16384 * 1024 * 2));
  if (o > ws_size) return;

  hipMemsetAsync(ws, 0, 768, stream);  // counts, cnt2, offs

  gating_kernel<<<512, 256, 0, stream>>>(x, nz, wg, wn, counts, rowinfo, loadrow, xb);
  transpose_cvt_kernel<<<dim3(64, 16, 8), 256, 0, stream>>>(W1, w1t, 1024, 4096);
  transpose_cvt_kernel<<<dim3(16, 64, 8), 256, 0, stream>>>(W2, w2t, 4096, 1024);
  scan_kernel<<<1, 64, 0, stream>>>(counts, offs, btab);
  fill_kernel<<<32, 256, 0, stream>>>(rowinfo, offs, cnt2, tok, slot_of);
  // ffn1: K=1024, bf16 out with bias+relu (nc=16 col tiles, kh always 0)
  ffn8_kernel<1024, true, true, false><<<dim3(72, 16), 512, 0, stream>>>(
      xb, w1t, b1, h_buf, counts, offs, btab, tok, 16, 1024, 4096, 0);
  // ffn2: K split 4x1024 in ONE dispatch (nc=4 col tiles x 4 kh), bf16 partials
  ffn8_kernel<4096, false, false, true><<<dim3(72, 16), 512, 0, stream>>>(
      h_buf, w2t, nullptr, pbuf, counts, offs, btab, tok, 4, 1024, 1024,
      (size_t)16384 * 1024);
  combine_kernel<<<8192, 256, 0, stream>>>(pbuf, b2, rowinfo, slot_of, y);
  loss1_kernel<<<32, 256, 0, stream>>>(rowinfo, loadrow, partials);
  loss2_kernel<<<1, 64, 0, stream>>>(partials, loss);
}